// Round 6
// baseline (3478.877 us; speedup 1.0000x reference)
//
#include <hip/hip_runtime.h>
#include <cstddef>
#include <cstdint>
#include <math.h>

#define EPSF 1e-8f

// Model dims (fixed): T=64, B=128, D=300, H=300, L=20, AH=300, N2=2B=256

// ---------------------------------------------------------------------------
// 128x128 NT GEMM, 8x8 micro, KT=16: C[m,n] = bias[n] + sum_k A[m,k]*B[n,k]
// ---------------------------------------------------------------------------
__global__ __launch_bounds__(256) void gemm_nt128(
    const float* __restrict__ A, const float* __restrict__ B,
    const float* __restrict__ bias, float* __restrict__ C,
    int M, int N, int K)
{
  __shared__ float As[16][128];
  __shared__ float Bs[16][128];
  const int tid = threadIdx.x;
  const int tx = tid & 15, ty = tid >> 4;
  const int mbase = blockIdx.y << 7, nbase = blockIdx.x << 7;
  const int lm = tid >> 1;          // 0..127
  const int lk = (tid & 1) << 3;    // 0 or 8
  float acc[8][8];
#pragma unroll
  for (int i = 0; i < 8; i++)
#pragma unroll
    for (int j = 0; j < 8; j++) acc[i][j] = 0.f;

  for (int kk = 0; kk < K; kk += 16) {
    {
      int m = mbase + lm;
      const float* src = A + (size_t)m * K;
#pragma unroll
      for (int q = 0; q < 2; q++) {
        int kb = kk + lk + q * 4;
        float4 v = make_float4(0.f, 0.f, 0.f, 0.f);
        if (m < M) {
          if (kb + 4 <= K) {
            v = *(const float4*)(src + kb);
          } else {
            v.x = (kb + 0 < K) ? src[kb + 0] : 0.f;
            v.y = (kb + 1 < K) ? src[kb + 1] : 0.f;
            v.z = (kb + 2 < K) ? src[kb + 2] : 0.f;
            v.w = (kb + 3 < K) ? src[kb + 3] : 0.f;
          }
        }
        As[lk + q * 4 + 0][lm] = v.x;
        As[lk + q * 4 + 1][lm] = v.y;
        As[lk + q * 4 + 2][lm] = v.z;
        As[lk + q * 4 + 3][lm] = v.w;
      }
    }
    {
      int n = nbase + lm;
      const float* src = B + (size_t)n * K;
#pragma unroll
      for (int q = 0; q < 2; q++) {
        int kb = kk + lk + q * 4;
        float4 v = make_float4(0.f, 0.f, 0.f, 0.f);
        if (n < N) {
          if (kb + 4 <= K) {
            v = *(const float4*)(src + kb);
          } else {
            v.x = (kb + 0 < K) ? src[kb + 0] : 0.f;
            v.y = (kb + 1 < K) ? src[kb + 1] : 0.f;
            v.z = (kb + 2 < K) ? src[kb + 2] : 0.f;
            v.w = (kb + 3 < K) ? src[kb + 3] : 0.f;
          }
        }
        Bs[lk + q * 4 + 0][lm] = v.x;
        Bs[lk + q * 4 + 1][lm] = v.y;
        Bs[lk + q * 4 + 2][lm] = v.z;
        Bs[lk + q * 4 + 3][lm] = v.w;
      }
    }
    __syncthreads();
#pragma unroll
    for (int k = 0; k < 16; k++) {
      float4 a0 = *(const float4*)&As[k][ty * 8];
      float4 a1 = *(const float4*)&As[k][ty * 8 + 4];
      float4 b0 = *(const float4*)&Bs[k][tx * 8];
      float4 b1 = *(const float4*)&Bs[k][tx * 8 + 4];
      float av[8] = {a0.x, a0.y, a0.z, a0.w, a1.x, a1.y, a1.z, a1.w};
      float bv[8] = {b0.x, b0.y, b0.z, b0.w, b1.x, b1.y, b1.z, b1.w};
#pragma unroll
      for (int i = 0; i < 8; i++)
#pragma unroll
        for (int j = 0; j < 8; j++) acc[i][j] += av[i] * bv[j];
    }
    __syncthreads();
  }

#pragma unroll
  for (int i = 0; i < 8; i++) {
    int m = mbase + ty * 8 + i;
    if (m >= M) continue;
#pragma unroll
    for (int jq = 0; jq < 2; jq++) {
      int n = nbase + tx * 8 + jq * 4;
      if (n >= N) continue;
      float4 v = make_float4(acc[i][jq * 4], acc[i][jq * 4 + 1],
                             acc[i][jq * 4 + 2], acc[i][jq * 4 + 3]);
      if (bias) {
        v.x += bias[n]; v.y += bias[n + 1]; v.z += bias[n + 2]; v.w += bias[n + 3];
      }
      *(float4*)(C + (size_t)m * N + n) = v;
    }
  }
}

// ---------------------------------------------------------------------------
// Transpose 3 weight matrices (1200,300) -> (300,1200). z selects matrix.
// ---------------------------------------------------------------------------
__global__ __launch_bounds__(256) void transpose3_kernel(
    const float* __restrict__ W0, const float* __restrict__ W1,
    const float* __restrict__ W2,
    float* __restrict__ T0, float* __restrict__ T1, float* __restrict__ T2)
{
  const float* W = (blockIdx.z == 0) ? W0 : (blockIdx.z == 1) ? W1 : W2;
  float* T = (blockIdx.z == 0) ? T0 : (blockIdx.z == 1) ? T1 : T2;
  __shared__ float tile[32][33];
  const int tx = threadIdx.x & 31, ty = threadIdx.x >> 5;  // 32 x 8
  const int nb = blockIdx.x * 32, kb = blockIdx.y * 32;
#pragma unroll
  for (int i = 0; i < 4; i++) {
    int n = nb + ty + i * 8, k = kb + tx;
    if (n < 1200 && k < 300) tile[ty + i * 8][tx] = W[(size_t)n * 300 + k];
  }
  __syncthreads();
#pragma unroll
  for (int i = 0; i < 4; i++) {
    int k = kb + ty + i * 8, n = nb + tx;
    if (n < 1200 && k < 300) T[(size_t)k * 1200 + n] = tile[tx][ty + i * 8];
  }
}

// ---------------------------------------------------------------------------
// Persistent LSTM v3: R=4 rows/block, all 64 steps. 480 threads = 3 K-splits
// (Kt=100) x 160 (150 active col-octets: 8 cols/thread -> 32 FMA per h-read).
// XCD-partitioned: xcd = b&7, dir = xcd>>2, row-group = (b>>3)*4 + (xcd&3).
// 4-k-deep weight prefetch (8 float4 in flight); gx loaded at step start,
// consumed at step end. g partials [s][r][1200] -> conflict-free LDS.
// LDS = 1200 + 3*4800 floats = 62.4 KB (1 block/CU).
// ---------------------------------------------------------------------------
__global__ __launch_bounds__(480, 1) void lstm_persist4(
    const float* __restrict__ WT0, const float* __restrict__ WT1,  // (300,1200)
    const float* __restrict__ gx0, const float* __restrict__ gx1,  // (64,NB,1200)
    float* __restrict__ hist0, float* __restrict__ hist1,          // (64,NB,300) or null
    float* __restrict__ hfin,                                      // (2,NB,300) or null
    int NB)
{
  const int b = blockIdx.x;
  const int xcd = b & 7;
  const int grp = b >> 3;
  const int dirb = xcd >> 2;
  const int n0 = (grp * 4 + (xcd & 3)) * 4;
  const int tid = threadIdx.x;
  const int s = tid / 160;        // 0..2 K-split
  const int c = tid - s * 160;    // 0..159, active if < 150
  const bool active = (c < 150);
  const int k0 = s * 100;

  const float* WT = dirb ? WT1 : WT0;
  const float* gx = dirb ? gx1 : gx0;
  float* hist = dirb ? hist1 : hist0;

  __shared__ float h_lds[1200];          // [k][r]
  __shared__ float g_lds[3][4][1200];    // [split][r][gatecol]

  float crs[3] = {0.f, 0.f, 0.f};        // c-state for up to 3 owned units

  for (int e = tid; e < 1200; e += 480) h_lds[e] = 0.f;
  __syncthreads();

  for (int t = 0; t < 64; t++) {
    const int tg = dirb ? (63 - t) : t;

    if (active) {
      // early-issue x-gate loads (s==0 only); consumed at partial write-back
      float4 gxa[4], gxb[4];
      if (s == 0) {
        const float* gxt = gx + ((size_t)tg * NB + n0) * 1200 + 8 * c;
#pragma unroll
        for (int r = 0; r < 4; r++) {
          gxa[r] = *(const float4*)(gxt + (size_t)r * 1200);
          gxb[r] = *(const float4*)(gxt + (size_t)r * 1200 + 4);
        }
      }

      float acc[4][8];
#pragma unroll
      for (int r = 0; r < 4; r++)
#pragma unroll
        for (int j = 0; j < 8; j++) acc[r][j] = 0.f;

      const float* wp = WT + (size_t)k0 * 1200 + 8 * c;
      float4 w[8], nx[8];
#pragma unroll
      for (int j = 0; j < 4; j++) {
        w[2 * j]     = *(const float4*)(wp + (size_t)j * 1200);
        w[2 * j + 1] = *(const float4*)(wp + (size_t)j * 1200 + 4);
      }
      const float* wpn = wp + 4 * 1200;

      for (int k = 0; k < 100; k += 4) {
        if (k + 4 < 100) {
#pragma unroll
          for (int j = 0; j < 4; j++) {
            nx[2 * j]     = *(const float4*)(wpn + (size_t)j * 1200);
            nx[2 * j + 1] = *(const float4*)(wpn + (size_t)j * 1200 + 4);
          }
          wpn += 4 * 1200;
        }
#pragma unroll
        for (int j = 0; j < 4; j++) {
          float4 hv = *(const float4*)&h_lds[(k0 + k + j) * 4];
          float4 w0 = w[2 * j], w1 = w[2 * j + 1];
          acc[0][0] += hv.x * w0.x; acc[0][1] += hv.x * w0.y; acc[0][2] += hv.x * w0.z; acc[0][3] += hv.x * w0.w;
          acc[0][4] += hv.x * w1.x; acc[0][5] += hv.x * w1.y; acc[0][6] += hv.x * w1.z; acc[0][7] += hv.x * w1.w;
          acc[1][0] += hv.y * w0.x; acc[1][1] += hv.y * w0.y; acc[1][2] += hv.y * w0.z; acc[1][3] += hv.y * w0.w;
          acc[1][4] += hv.y * w1.x; acc[1][5] += hv.y * w1.y; acc[1][6] += hv.y * w1.z; acc[1][7] += hv.y * w1.w;
          acc[2][0] += hv.z * w0.x; acc[2][1] += hv.z * w0.y; acc[2][2] += hv.z * w0.z; acc[2][3] += hv.z * w0.w;
          acc[2][4] += hv.z * w1.x; acc[2][5] += hv.z * w1.y; acc[2][6] += hv.z * w1.z; acc[2][7] += hv.z * w1.w;
          acc[3][0] += hv.w * w0.x; acc[3][1] += hv.w * w0.y; acc[3][2] += hv.w * w0.z; acc[3][3] += hv.w * w0.w;
          acc[3][4] += hv.w * w1.x; acc[3][5] += hv.w * w1.y; acc[3][6] += hv.w * w1.z; acc[3][7] += hv.w * w1.w;
        }
#pragma unroll
        for (int j = 0; j < 8; j++) w[j] = nx[j];
      }

      // partial write-back: g_lds[s][r][8c..8c+7]  (lane stride 32B: free 2-way)
#pragma unroll
      for (int r = 0; r < 4; r++) {
        float4 v0 = make_float4(acc[r][0], acc[r][1], acc[r][2], acc[r][3]);
        float4 v1 = make_float4(acc[r][4], acc[r][5], acc[r][6], acc[r][7]);
        if (s == 0) {
          v0.x += gxa[r].x; v0.y += gxa[r].y; v0.z += gxa[r].z; v0.w += gxa[r].w;
          v1.x += gxb[r].x; v1.y += gxb[r].y; v1.z += gxb[r].z; v1.w += gxb[r].w;
        }
        *(float4*)&g_lds[s][r][8 * c]     = v0;
        *(float4*)&g_lds[s][r][8 * c + 4] = v1;
      }
    }
    __syncthreads();

    // elementwise: up to 3 units/thread; conflict-free consecutive-k reads
#pragma unroll
    for (int q = 0; q < 3; q++) {
      int u = tid + q * 480;
      if (u < 1200) {
        int r = u / 300, k = u - r * 300;
        float gi = g_lds[0][r][k]       + g_lds[1][r][k]       + g_lds[2][r][k];
        float gf = g_lds[0][r][300 + k] + g_lds[1][r][300 + k] + g_lds[2][r][300 + k];
        float gg = g_lds[0][r][600 + k] + g_lds[1][r][600 + k] + g_lds[2][r][600 + k];
        float go = g_lds[0][r][900 + k] + g_lds[1][r][900 + k] + g_lds[2][r][900 + k];
        float si = 1.f / (1.f + expf(-gi));
        float sf = 1.f / (1.f + expf(-gf));
        float so = 1.f / (1.f + expf(-go));
        float cc = sf * crs[q] + si * tanhf(gg);
        float h = so * tanhf(cc);
        crs[q] = cc;
        h_lds[k * 4 + r] = h;
        if (hist) hist[((size_t)tg * NB + n0 + r) * 300 + k] = h;
      }
    }
    __syncthreads();
  }

  if (hfin) {
#pragma unroll
    for (int q = 0; q < 3; q++) {
      int u = tid + q * 480;
      if (u < 1200) {
        int r = u / 300, k = u - r * 300;
        hfin[((size_t)dirb * NB + n0 + r) * 300 + k] = h_lds[k * 4 + r];
      }
    }
  }
}

// ---------------------------------------------------------------------------
__global__ void embed_kernel(
    const int* __restrict__ prem, const int* __restrict__ hyp,
    const float* __restrict__ embW, float* __restrict__ comb)
{
  size_t i = (size_t)blockIdx.x * 256 + threadIdx.x;
  if (i >= (size_t)64 * 256 * 75) return;
  int d4 = (int)(i % 75);
  size_t r = i / 75;
  int n = (int)(r % 256);
  int t = (int)(r / 256);
  int id = (n < 128) ? prem[t * 128 + n] : hyp[t * 128 + (n - 128)];
  float4 v = *(const float4*)(embW + (size_t)id * 300 + d4 * 4);
  *(float4*)(comb + ((size_t)t * 256 + n) * 300 + d4 * 4) = v;
}

// ---------------------------------------------------------------------------
// norm4: weighted norms for all four W sets per (dir,t,n,l) + plain row norms.
// ---------------------------------------------------------------------------
__global__ __launch_bounds__(320) void norm4_kernel(
    const float* __restrict__ hs_fw, const float* __restrict__ hs_bw,
    const float* __restrict__ mp_W,
    float* __restrict__ nm4, float* __restrict__ pnorm)
{
  const int t = blockIdx.x, n = blockIdx.y, dir = blockIdx.z;
  const float* HS = dir ? hs_bw : hs_fw;
  const float* row = HS + ((size_t)t * 256 + n) * 300;
  __shared__ float sh[300];
  const int tid = threadIdx.x, g = tid >> 4, lane = tid & 15;
  for (int k = tid; k < 300; k += 320) sh[k] = row[k];
  __syncthreads();
  if (g == 0) {
    float s2 = 0.f;
    for (int k = lane; k < 300; k += 16) { float x = sh[k]; s2 += x * x; }
    for (int o = 8; o; o >>= 1) s2 += __shfl_down(s2, o, 16);
    if (lane == 0) pnorm[((size_t)dir * 64 + t) * 256 + n] = sqrtf(s2);
  }
#pragma unroll
  for (int wset = 0; wset < 4; wset++) {
    const float* W = mp_W + dir * 24000 + wset * 6000 + g * 300;
    float s1 = 0.f;
    for (int k = lane; k < 300; k += 16) {
      float x = sh[k];
      float w = W[k];
      s1 += x * x * w * w;
    }
    for (int o = 8; o; o >>= 1) s1 += __shfl_down(s1, o, 16);
    if (lane == 0)
      nm4[((((size_t)dir * 4 + wset) * 64 + t) * 256 + n) * 20 + g] = sqrtf(s1);
  }
}

// ---------------------------------------------------------------------------
// att: per (b,z), att[64,64] cosine GEMM -> normalized w (watt) + argmax idx.
// ---------------------------------------------------------------------------
__global__ __launch_bounds__(256) void att_kernel(
    const float* __restrict__ hs_fw, const float* __restrict__ hs_bw,
    const float* __restrict__ pnorm,
    float* __restrict__ watt, int* __restrict__ idxbuf)
{
  const int b = blockIdx.x, z = blockIdx.y;
  const int dir = z & 1;
  const float* HS = dir ? hs_bw : hs_fw;
  const int p_n = (z < 2) ? b : 128 + b;
  const int h_n = (z < 2) ? 128 + b : b;
  const float* pnD = pnorm + (size_t)dir * 16384;

  __shared__ float pch[64 * 100];
  __shared__ float hch[64 * 100];
  __shared__ float att[64 * 65];
  __shared__ float winv_sh[64];

  const int tid = threadIdx.x;
  const int i = tid >> 4, j = tid & 15;
  float acc[4][4];
#pragma unroll
  for (int a = 0; a < 4; a++)
#pragma unroll
    for (int c = 0; c < 4; c++) acc[a][c] = 0.f;

  for (int kc = 0; kc < 300; kc += 100) {
    for (int e = tid; e < 1600; e += 256) {
      int row = e / 25, kq = e - row * 25;
      float4 v = *(const float4*)(HS + ((size_t)row * 256 + p_n) * 300 + kc + kq * 4);
      *(float4*)&pch[row * 100 + kq * 4] = v;
      float4 w = *(const float4*)(HS + ((size_t)row * 256 + h_n) * 300 + kc + kq * 4);
      *(float4*)&hch[row * 100 + kq * 4] = w;
    }
    __syncthreads();
#pragma unroll 5
    for (int kq = 0; kq < 25; kq++) {
      float4 av[4], bv[4];
#pragma unroll
      for (int a = 0; a < 4; a++) av[a] = *(const float4*)&pch[(i + 16 * a) * 100 + kq * 4];
#pragma unroll
      for (int c = 0; c < 4; c++) bv[c] = *(const float4*)&hch[(j + 16 * c) * 100 + kq * 4];
#pragma unroll
      for (int a = 0; a < 4; a++)
#pragma unroll
        for (int c = 0; c < 4; c++)
          acc[a][c] += av[a].x * bv[c].x + av[a].y * bv[c].y + av[a].z * bv[c].z + av[a].w * bv[c].w;
    }
    __syncthreads();
  }

#pragma unroll
  for (int a = 0; a < 4; a++) {
    int t = i + 16 * a;
    float pn = pnD[t * 256 + p_n] + EPSF;
#pragma unroll
    for (int c = 0; c < 4; c++) {
      int s = j + 16 * c;
      float hn = pnD[s * 256 + h_n] + EPSF;
      att[t * 65 + s] = acc[a][c] / (pn * hn);
    }
  }
  __syncthreads();
  if (tid < 64) {
    int t = tid;
    float ssum = 0.f, mx = -1e30f; int mi = 0;
    for (int s = 0; s < 64; s++) {
      float a = att[t * 65 + s];
      ssum += a;
      if (a > mx) { mx = a; mi = s; }
    }
    winv_sh[t] = 1.f / (ssum + EPSF);
    idxbuf[((size_t)z * 128 + b) * 64 + t] = mi;
  }
  __syncthreads();
  for (int e = tid; e < 4096; e += 256) {
    int t = e >> 6, s = e & 63;
    watt[((size_t)z * 128 + b) * 4096 + t * 64 + s] = att[t * 65 + s] * winv_sh[t];
  }
}

// ---------------------------------------------------------------------------
// hmean: per (b,z): hmean[t,k] = sum_s w[t,s]*h[s,k]
// ---------------------------------------------------------------------------
__global__ __launch_bounds__(256) void hmean_kernel(
    const float* __restrict__ hs_fw, const float* __restrict__ hs_bw,
    const float* __restrict__ watt, float* __restrict__ hmeanbuf)
{
  const int b = blockIdx.x, z = blockIdx.y;
  const int dir = z & 1;
  const float* HS = dir ? hs_bw : hs_fw;
  const int h_n = (z < 2) ? 128 + b : b;

  __shared__ float wsh[64 * 65];
  __shared__ float hch[64 * 128];

  const int tid = threadIdx.x;
  const int ti = tid >> 4, kj = tid & 15;
  const float* wsrc = watt + ((size_t)z * 128 + b) * 4096;
  for (int e = tid; e < 4096; e += 256) {
    int t = e >> 6, s = e & 63;
    wsh[t * 65 + s] = wsrc[t * 64 + s];
  }

  for (int kbase = 0; kbase < 300; kbase += 128) {
    int kw = min(128, 300 - kbase);
    int nf4 = kw >> 2;  // 32,32,11
    __syncthreads();
    for (int e = tid; e < 64 * nf4; e += 256) {
      int row = e / nf4, q = e - row * nf4;
      float4 v = *(const float4*)(HS + ((size_t)row * 256 + h_n) * 300 + kbase + q * 4);
      *(float4*)&hch[row * 128 + q * 4] = v;
    }
    __syncthreads();
    float acc[4][8];
#pragma unroll
    for (int a = 0; a < 4; a++)
#pragma unroll
      for (int c = 0; c < 8; c++) acc[a][c] = 0.f;
    for (int s = 0; s < 64; s++) {
      float4 h0 = *(const float4*)&hch[s * 128 + 4 * kj];
      float4 h1 = *(const float4*)&hch[s * 128 + 4 * (kj + 16)];
#pragma unroll
      for (int a = 0; a < 4; a++) {
        float w = wsh[(4 * ti + a) * 65 + s];
        acc[a][0] += w * h0.x; acc[a][1] += w * h0.y; acc[a][2] += w * h0.z; acc[a][3] += w * h0.w;
        acc[a][4] += w * h1.x; acc[a][5] += w * h1.y; acc[a][6] += w * h1.z; acc[a][7] += w * h1.w;
      }
    }
#pragma unroll
    for (int a = 0; a < 4; a++) {
      int t = 4 * ti + a;
#pragma unroll
      for (int c = 0; c < 2; c++) {
        int kq = kj + 16 * c;
        if (kq * 4 < kw) {
          int k = kbase + kq * 4;
          float4 v = make_float4(acc[a][4 * c], acc[a][4 * c + 1], acc[a][4 * c + 2], acc[a][4 * c + 3]);
          *(float4*)&hmeanbuf[(((size_t)z * 128 + b) * 64 + t) * 300 + k] = v;
        }
      }
    }
  }
}

// ---------------------------------------------------------------------------
// maxp: per (b,z,tt): num[t,s,l] GEMM with register tiles, fused max over s.
// ---------------------------------------------------------------------------
__global__ __launch_bounds__(128) void maxp_kernel(
    const float* __restrict__ hs_fw, const float* __restrict__ hs_bw,
    const float* __restrict__ mp_W, const float* __restrict__ nm4,
    float* __restrict__ m_out)
{
  const int b = blockIdx.x, z = blockIdx.y, tt = blockIdx.z;
  const int dir = z & 1;
  const float* HS = dir ? hs_bw : hs_fw;
  const int p_n = (z < 2) ? b : 128 + b;
  const int h_n = (z < 2) ? 128 + b : b;
  const int t_base = tt * 8;
  const float* Wm = mp_W + dir * 24000 + 6000;

  __shared__ float psh[8 * 100];
  __shared__ float hsh[64 * 100];
  __shared__ float wsh[20 * 100];

  const int tid = threadIdx.x;
  const int t_loc = tid >> 4;
  const int sg = (tid >> 1) & 7;
  const int lg = tid & 1;
  const int t = t_base + t_loc;

  float acc[8][10];
#pragma unroll
  for (int i = 0; i < 8; i++)
#pragma unroll
    for (int j = 0; j < 10; j++) acc[i][j] = 0.f;

  for (int kc = 0; kc < 300; kc += 100) {
    for (int e = tid; e < 200; e += 128) {
      int row = e / 25, q = e - row * 25;
      float4 v = *(const float4*)(HS + ((size_t)(t_base + row) * 256 + p_n) * 300 + kc + q * 4);
      *(float4*)&psh[row * 100 + q * 4] = v;
    }
    for (int e = tid; e < 1600; e += 128) {
      int row = e / 25, q = e - row * 25;
      float4 v = *(const float4*)(HS + ((size_t)row * 256 + h_n) * 300 + kc + q * 4);
      *(float4*)&hsh[row * 100 + q * 4] = v;
    }
    for (int e = tid; e < 500; e += 128) {
      int row = e / 25, q = e - row * 25;
      float4 w = *(const float4*)(Wm + (size_t)row * 300 + kc + q * 4);
      w.x *= w.x; w.y *= w.y; w.z *= w.z; w.w *= w.w;
      *(float4*)&wsh[row * 100 + q * 4] = w;
    }
    __syncthreads();
    for (int kq = 0; kq < 25; kq++) {
      float4 pv = *(const float4*)&psh[t_loc * 100 + kq * 4];
      float4 hv[8];
#pragma unroll
      for (int i = 0; i < 8; i++) hv[i] = *(const float4*)&hsh[(sg + 8 * i) * 100 + kq * 4];
#pragma unroll
      for (int j = 0; j < 10; j++) {
        float4 wv = *(const float4*)&wsh[(lg * 10 + j) * 100 + kq * 4];
        float pwx = pv.x * wv.x, pwy = pv.y * wv.y, pwz = pv.z * wv.z, pww = pv.w * wv.w;
#pragma unroll
        for (int i = 0; i < 8; i++)
          acc[i][j] += hv[i].x * pwx + hv[i].y * pwy + hv[i].z * pwz + hv[i].w * pww;
      }
    }
    __syncthreads();
  }

  const float* nmD = nm4 + ((size_t)dir * 4 + 1) * 327680;
  float pn[10], rmax[10];
#pragma unroll
  for (int j = 0; j < 10; j++) {
    pn[j] = nmD[((size_t)t * 256 + p_n) * 20 + lg * 10 + j];
    rmax[j] = -1e30f;
  }
#pragma unroll
  for (int i = 0; i < 8; i++) {
    int s = sg + 8 * i;
#pragma unroll
    for (int j = 0; j < 10; j++) {
      float hn = nmD[((size_t)s * 256 + h_n) * 20 + lg * 10 + j];
      float r = acc[i][j] / (pn[j] * hn + EPSF);
      rmax[j] = fmaxf(rmax[j], r);
    }
  }
#pragma unroll
  for (int off = 8; off >= 2; off >>= 1)
#pragma unroll
    for (int j = 0; j < 10; j++)
      rmax[j] = fmaxf(rmax[j], __shfl_down(rmax[j], off));
  if (sg == 0) {
    float* mrow = m_out + ((size_t)t * 128 + b) * 320 + z * 80;
#pragma unroll
    for (int j = 0; j < 10; j++) mrow[20 + lg * 10 + j] = rmax[j];
  }
}

// ---------------------------------------------------------------------------
// rest: per (b,z): full / attm / maxattm for all t. W^2 staged once in LDS.
// ---------------------------------------------------------------------------
__global__ __launch_bounds__(320) void rest_kernel(
    const float* __restrict__ hs_fw, const float* __restrict__ hs_bw,
    const float* __restrict__ mp_W, const float* __restrict__ nm4,
    const float* __restrict__ hmeanbuf, const int* __restrict__ idxbuf,
    float* __restrict__ m_out)
{
  const int b = blockIdx.x, z = blockIdx.y;
  const int dir = z & 1;
  const float* HS = dir ? hs_bw : hs_fw;
  const int p_n = (z < 2) ? b : 128 + b;
  const int h_n = (z < 2) ? 128 + b : b;
  const int v_t = dir ? 0 : 63;

  __shared__ float w2f[6000], w2a[6000], w2m[6000];
  __shared__ float vsh[300], psh[300], hmsh[300], hxsh[300];

  const int tid = threadIdx.x;
  const int g = tid >> 4, lane = tid & 15;
  const float* Wf = mp_W + dir * 24000;
  const float* Wa = Wf + 12000;
  const float* Wma = Wf + 18000;
  for (int e = tid; e < 6000; e += 320) {
    float a = Wf[e], bb = Wa[e], c = Wma[e];
    w2f[e] = a * a; w2a[e] = bb * bb; w2m[e] = c * c;
  }
  for (int e = tid; e < 300; e += 320)
    vsh[e] = HS[((size_t)v_t * 256 + h_n) * 300 + e];
  __syncthreads();

  const float* base0 = nm4 + ((size_t)dir * 4 + 0) * 327680;
  const float* base2 = nm4 + ((size_t)dir * 4 + 2) * 327680;
  const float* base3 = nm4 + ((size_t)dir * 4 + 3) * 327680;
  const float vnf = base0[((size_t)v_t * 256 + h_n) * 20 + g];

  for (int t = 0; t < 64; t++) {
    int idx = idxbuf[((size_t)z * 128 + b) * 64 + t];
    __syncthreads();
    for (int e = tid; e < 300; e += 320) {
      psh[e] = HS[((size_t)t * 256 + p_n) * 300 + e];
      hmsh[e] = hmeanbuf[(((size_t)z * 128 + b) * 64 + t) * 300 + e];
      hxsh[e] = HS[((size_t)idx * 256 + h_n) * 300 + e];
    }
    __syncthreads();
    float nf = 0.f, na = 0.f, qa = 0.f, nm = 0.f;
#pragma unroll
    for (int c = 0; c < 5; c++) {
      int k4 = lane + 16 * c;
      if (k4 < 75) {
        float4 p = *(const float4*)&psh[4 * k4];
        float4 v = *(const float4*)&vsh[4 * k4];
        float4 hm = *(const float4*)&hmsh[4 * k4];
        float4 hx = *(const float4*)&hxsh[4 * k4];
        float4 wf = *(const float4*)&w2f[g * 300 + 4 * k4];
        float4 wa = *(const float4*)&w2a[g * 300 + 4 * k4];
        float4 wm = *(const float4*)&w2m[g * 300 + 4 * k4];
        nf += p.x * v.x * wf.x + p.y * v.y * wf.y + p.z * v.z * wf.z + p.w * v.w * wf.w;
        na += p.x * hm.x * wa.x + p.y * hm.y * wa.y + p.z * hm.z * wa.z + p.w * hm.w * wa.w;
        qa += hm.x * hm.x * wa.x + hm.y * hm.y * wa.y + hm.z * hm.z * wa.z + hm.w * hm.w * wa.w;
        nm += p.x * hx.x * wm.x + p.y * hx.y * wm.y + p.z * hx.z * wm.z + p.w * hx.w * wm.w;
      }
    }
#pragma unroll
    for (int o = 8; o; o >>= 1) {
      nf += __shfl_down(nf, o);
      na += __shfl_down(na, o);
      qa += __shfl_down(qa, o);
      nm += __shfl_down(nm, o);
    }
    if (lane == 0) {
      float pnf = base0[((size_t)t * 256 + p_n) * 20 + g];
      float pna = base2[((size_t)t * 256 + p_n) * 20 + g];
      float pnm = base3[((size_t)t * 256 + p_n) * 20 + g];
      float qnm = base3[((size_t)idx * 256 + h_n) * 20 + g];
      float* mrow = m_out + ((size_t)t * 128 + b) * 320 + z * 80;
      mrow[g] = nf / (pnf * vnf + EPSF);
      mrow[40 + g] = na / (pna * sqrtf(qa) + EPSF);
      mrow[60 + g] = nm / (pnm * qnm + EPSF);
    }
  }
}

// ---------------------------------------------------------------------------
__global__ __launch_bounds__(256) void mlp_kernel(
    const float* __restrict__ shA0, const float* __restrict__ shA1,
    const float* __restrict__ bnG, const float* __restrict__ bnB,
    const float* __restrict__ W1, const float* __restrict__ b1,
    const float* __restrict__ W2, const float* __restrict__ b2,
    const float* __restrict__ outW, const float* __restrict__ outb,
    float* __restrict__ out)
{
  const int b = blockIdx.x;
  const int tid = threadIdx.x;
  __shared__ float x0[600], x1[600];
  const float inv = 1.0f / sqrtf(1.0f + 1e-5f);
  for (int j = tid; j < 600; j += 256) {
    float v = (j < 300) ? shA0[b * 300 + j] : shA1[b * 300 + (j - 300)];
    x0[j] = bnG[j] * v * inv + bnB[j];
  }
  __syncthreads();
  for (int j = tid; j < 600; j += 256) {
    float acc = b1[j];
    const float* w = W1 + (size_t)j * 600;
    for (int k = 0; k < 600; k++) acc += x0[k] * w[k];
    float r = fmaxf(acc, 0.f);
    x1[j] = bnG[600 + j] * r * inv + bnB[600 + j];
  }
  __syncthreads();
  for (int j = tid; j < 600; j += 256) {
    float acc = b2[j];
    const float* w = W2 + (size_t)j * 600;
    for (int k = 0; k < 600; k++) acc += x1[k] * w[k];
    float r = fmaxf(acc, 0.f);
    x0[j] = bnG[1200 + j] * r * inv + bnB[1200 + j];
  }
  __syncthreads();
  if (tid < 3) {
    float acc = outb[tid];
    const float* w = outW + tid * 600;
    for (int k = 0; k < 600; k++) acc += x0[k] * w[k];
    out[b * 3 + tid] = acc;
  }
}

// ---------------------------------------------------------------------------
extern "C" void kernel_launch(void* const* d_in, const int* in_sizes, int n_in,
                              void* d_out, int out_size, void* d_ws, size_t ws_size,
                              hipStream_t stream) {
  const int* premise = (const int*)d_in[0];
  const int* hypothesis = (const int*)d_in[1];
  const float* embW = (const float*)d_in[2];
  const float* cWih = (const float*)d_in[3];
  const float* cWhh = (const float*)d_in[4];
  const float* cb = (const float*)d_in[5];
  const float* mpW = (const float*)d_in[6];
  const float* aWihF = (const float*)d_in[7];
  const float* aWhhF = (const float*)d_in[8];
  const float* abF = (const float*)d_in[9];
  const float* aWihB = (const float*)d_in[10];
  const float* aWhhB = (const float*)d_in[11];
  const float* abB = (const float*)d_in[12];
  const float* bnG = (const float*)d_in[13];
  const float* bnB = (const float*)d_in[14];
  const float* W1 = (const float*)d_in[15];
  const float* b1 = (const float*)d_in[16];
  const float* W2 = (const float*)d_in[17];
  const float* b2 = (const float*)d_in[18];
  const float* outW = (const float*)d_in[19];
  const float* outb = (const float*)d_in[20];
  float* out = (float*)d_out;

  float* ws = (float*)d_ws;
  // workspace layout (floats)
  float* comb  = ws + 0;           // 4,915,200  (T,256,300); WhhT overlays after ctx-gates GEMM
  float* gates = ws + 4915200;     // 19,660,800 (T,256,1200); overlaid after ctx LSTM
  float* hsfw  = ws + 24576000;    // 4,915,200
  float* hsbw  = ws + 29491200;    // 4,915,200
  float* pnorm = ws + 34406400;    // 32,768    [2][64][256]
  float* mbuf  = ws + 35094528;    // 2,621,440 (T,128,320)
  float* sha   = ws + 38023168;    // 76,800    agg final h [2][128][300]

  // WhhT overlays in comb region (comb dead after ctx-gates GEMM)
  float* WTctx = comb;             // 360,000 (300,1200)
  float* WTaf  = comb + 360000;    // 360,000
  float* WTab  = comb + 720000;    // 360,000

  // overlays inside the dead ctx-gates region (valid between ctx LSTM and agg GEMMs)
  float* watt     = gates;                 // 2,097,152 [4][128][64][64]
  float* hmeanbuf = gates + 2097152;       // 9,830,400 [4][128][64][300]
  int*   idxbuf   = (int*)(gates + 11927552); // 32,768 [4][128][64]
  float* nm4      = gates + 11960320;      // 2,621,440 [2][4][64][256][20]

  // 1) embed
  embed_kernel<<<dim3(4800), dim3(256), 0, stream>>>(premise, hypothesis, embW, comb);

  // 2) ctx input gates (consumes comb)
  gemm_nt128<<<dim3(10, 128), dim3(256), 0, stream>>>(comb, cWih, cb, gates, 16384, 1200, 300);

  // 3) transpose recurrent weights into dead comb region
  transpose3_kernel<<<dim3(38, 10, 3), dim3(256), 0, stream>>>(
      cWhh, aWhhF, aWhhB, WTctx, WTaf, WTab);

  // 4) context LSTM: persistent, R=4, 128 blocks, XCD-partitioned dirs
  lstm_persist4<<<dim3(128), dim3(480), 0, stream>>>(
      WTctx, WTctx, gates, gates, hsfw, hsbw, nullptr, 256);

  // 5) norms (all 4 W sets) + plain norms
  norm4_kernel<<<dim3(64, 256, 2), dim3(320), 0, stream>>>(hsfw, hsbw, mpW, nm4, pnorm);

  // 6) matching pipeline
  att_kernel<<<dim3(128, 4), dim3(256), 0, stream>>>(hsfw, hsbw, pnorm, watt, idxbuf);
  hmean_kernel<<<dim3(128, 4), dim3(256), 0, stream>>>(hsfw, hsbw, watt, hmeanbuf);
  maxp_kernel<<<dim3(128, 4, 8), dim3(128), 0, stream>>>(hsfw, hsbw, mpW, nm4, mbuf);
  rest_kernel<<<dim3(128, 4), dim3(320), 0, stream>>>(hsfw, hsbw, mpW, nm4, hmeanbuf, idxbuf, mbuf);

  // 7) agg input gates (overwrite gates region; overlays fully consumed)
  float* gaf = gates;
  float* gab = gates + 9830400;
  gemm_nt128<<<dim3(10, 64), dim3(256), 0, stream>>>(mbuf, aWihF, abF, gaf, 8192, 1200, 320);
  gemm_nt128<<<dim3(10, 64), dim3(256), 0, stream>>>(mbuf, aWihB, abB, gab, 8192, 1200, 320);

  // 8) aggregation LSTM: persistent, R=4, 64 blocks, XCD-partitioned dirs
  lstm_persist4<<<dim3(64), dim3(480), 0, stream>>>(
      WTaf, WTab, gaf, gab, nullptr, nullptr, sha, 128);

  // 9) MLP head
  mlp_kernel<<<dim3(128), dim3(256), 0, stream>>>(
      sha, sha + 38400, bnG, bnB, W1, b1, W2, b2, outW, outb, out);
}

// Round 7
// 3158.026 us; speedup vs baseline: 1.1016x; 1.1016x over previous
//
#include <hip/hip_runtime.h>
#include <cstddef>
#include <cstdint>
#include <math.h>

#define EPSF 1e-8f

// Model dims (fixed): T=64, B=128, D=300, H=300, L=20, AH=300, N2=2B=256

typedef _Float16 half2v __attribute__((ext_vector_type(2)));
union F4H2 { float4 f; half2v h[4]; };

#if defined(__has_builtin)
#if __has_builtin(__builtin_amdgcn_fdot2)
#define HAVE_FDOT2 1
#endif
#endif

__device__ __forceinline__ float fdot2f(half2v a, half2v b, float c) {
#ifdef HAVE_FDOT2
  return __builtin_amdgcn_fdot2(a, b, c, false);
#else
  return c + (float)a.x * (float)b.x + (float)a.y * (float)b.y;
#endif
}

// ---------------------------------------------------------------------------
// 128x128 NT GEMM, 8x8 micro, KT=16: C[m,n] = bias[n] + sum_k A[m,k]*B[n,k]
// ---------------------------------------------------------------------------
__global__ __launch_bounds__(256) void gemm_nt128(
    const float* __restrict__ A, const float* __restrict__ B,
    const float* __restrict__ bias, float* __restrict__ C,
    int M, int N, int K)
{
  __shared__ float As[16][128];
  __shared__ float Bs[16][128];
  const int tid = threadIdx.x;
  const int tx = tid & 15, ty = tid >> 4;
  const int mbase = blockIdx.y << 7, nbase = blockIdx.x << 7;
  const int lm = tid >> 1;          // 0..127
  const int lk = (tid & 1) << 3;    // 0 or 8
  float acc[8][8];
#pragma unroll
  for (int i = 0; i < 8; i++)
#pragma unroll
    for (int j = 0; j < 8; j++) acc[i][j] = 0.f;

  for (int kk = 0; kk < K; kk += 16) {
    {
      int m = mbase + lm;
      const float* src = A + (size_t)m * K;
#pragma unroll
      for (int q = 0; q < 2; q++) {
        int kb = kk + lk + q * 4;
        float4 v = make_float4(0.f, 0.f, 0.f, 0.f);
        if (m < M) {
          if (kb + 4 <= K) {
            v = *(const float4*)(src + kb);
          } else {
            v.x = (kb + 0 < K) ? src[kb + 0] : 0.f;
            v.y = (kb + 1 < K) ? src[kb + 1] : 0.f;
            v.z = (kb + 2 < K) ? src[kb + 2] : 0.f;
            v.w = (kb + 3 < K) ? src[kb + 3] : 0.f;
          }
        }
        As[lk + q * 4 + 0][lm] = v.x;
        As[lk + q * 4 + 1][lm] = v.y;
        As[lk + q * 4 + 2][lm] = v.z;
        As[lk + q * 4 + 3][lm] = v.w;
      }
    }
    {
      int n = nbase + lm;
      const float* src = B + (size_t)n * K;
#pragma unroll
      for (int q = 0; q < 2; q++) {
        int kb = kk + lk + q * 4;
        float4 v = make_float4(0.f, 0.f, 0.f, 0.f);
        if (n < N) {
          if (kb + 4 <= K) {
            v = *(const float4*)(src + kb);
          } else {
            v.x = (kb + 0 < K) ? src[kb + 0] : 0.f;
            v.y = (kb + 1 < K) ? src[kb + 1] : 0.f;
            v.z = (kb + 2 < K) ? src[kb + 2] : 0.f;
            v.w = (kb + 3 < K) ? src[kb + 3] : 0.f;
          }
        }
        Bs[lk + q * 4 + 0][lm] = v.x;
        Bs[lk + q * 4 + 1][lm] = v.y;
        Bs[lk + q * 4 + 2][lm] = v.z;
        Bs[lk + q * 4 + 3][lm] = v.w;
      }
    }
    __syncthreads();
#pragma unroll
    for (int k = 0; k < 16; k++) {
      float4 a0 = *(const float4*)&As[k][ty * 8];
      float4 a1 = *(const float4*)&As[k][ty * 8 + 4];
      float4 b0 = *(const float4*)&Bs[k][tx * 8];
      float4 b1 = *(const float4*)&Bs[k][tx * 8 + 4];
      float av[8] = {a0.x, a0.y, a0.z, a0.w, a1.x, a1.y, a1.z, a1.w};
      float bv[8] = {b0.x, b0.y, b0.z, b0.w, b1.x, b1.y, b1.z, b1.w};
#pragma unroll
      for (int i = 0; i < 8; i++)
#pragma unroll
        for (int j = 0; j < 8; j++) acc[i][j] += av[i] * bv[j];
    }
    __syncthreads();
  }

#pragma unroll
  for (int i = 0; i < 8; i++) {
    int m = mbase + ty * 8 + i;
    if (m >= M) continue;
#pragma unroll
    for (int jq = 0; jq < 2; jq++) {
      int n = nbase + tx * 8 + jq * 4;
      if (n >= N) continue;
      float4 v = make_float4(acc[i][jq * 4], acc[i][jq * 4 + 1],
                             acc[i][jq * 4 + 2], acc[i][jq * 4 + 3]);
      if (bias) {
        v.x += bias[n]; v.y += bias[n + 1]; v.z += bias[n + 2]; v.w += bias[n + 3];
      }
      *(float4*)(C + (size_t)m * N + n) = v;
    }
  }
}

// ---------------------------------------------------------------------------
// pack3: W (1200,300) fp32 -> WT2 packed f16 k-pairs: WT2[k2*1200+n] =
// half2(W[n][2k2], W[n][2k2+1]).  blockIdx.y selects matrix.
// ---------------------------------------------------------------------------
__global__ __launch_bounds__(256) void pack3_kernel(
    const float* __restrict__ W0, const float* __restrict__ W1,
    const float* __restrict__ W2,
    unsigned* __restrict__ T0, unsigned* __restrict__ T1,
    unsigned* __restrict__ T2)
{
  int i = blockIdx.x * 256 + threadIdx.x;
  if (i >= 180000) return;
  const float* W = (blockIdx.y == 0) ? W0 : (blockIdx.y == 1) ? W1 : W2;
  unsigned* T = (blockIdx.y == 0) ? T0 : (blockIdx.y == 1) ? T1 : T2;
  int k2 = i / 1200, n = i - k2 * 1200;
  float a = W[(size_t)n * 300 + 2 * k2];
  float b = W[(size_t)n * 300 + 2 * k2 + 1];
  union { half2v h; unsigned u; } v;
  v.h.x = (_Float16)a;
  v.h.y = (_Float16)b;
  T[i] = v.u;
}

// ---------------------------------------------------------------------------
// Persistent LSTM v4 (f16 weights + dot2): R=4 rows/block, all 64 steps.
// 480 threads = 3 K-splits (50 k-pairs) x 160 (150 active col-octets).
// XCD-partitioned: xcd = b&7, dir = xcd>>2, row-group = (b>>3)*4 + (xcd&3).
// Weights packed half2 (k-pairs); h kept in LDS as packed half2 per (k2,r).
// fp32 accumulate + fp32 c-state + fp32 hist/hfin outputs.
// 1-group-deep register pipeline (5 k-pairs/group) for w (global) and h (LDS).
// LDS = 600*4 + 3*4*1200*4 = 60.0 KB.
// ---------------------------------------------------------------------------
__global__ __launch_bounds__(480, 1) void lstm_persist5(
    const uint4* __restrict__ WT0, const uint4* __restrict__ WT1,  // packed (150,1200)
    const float* __restrict__ gx0, const float* __restrict__ gx1,  // (64,NB,1200)
    float* __restrict__ hist0, float* __restrict__ hist1,          // (64,NB,300) or null
    float* __restrict__ hfin,                                      // (2,NB,300) or null
    int NB)
{
  const int b = blockIdx.x;
  const int xcd = b & 7;
  const int grp = b >> 3;
  const int dirb = xcd >> 2;
  const int n0 = (grp * 4 + (xcd & 3)) * 4;
  const int tid = threadIdx.x;
  const int s = tid / 160;        // 0..2 K-split
  const int c = tid - s * 160;    // 0..159, active if < 150
  const bool active = (c < 150);
  const int k2base = s * 50;      // k-pair base

  const uint4* WT = dirb ? WT1 : WT0;
  const float* gx = dirb ? gx1 : gx0;
  float* hist = dirb ? hist1 : hist0;

  __shared__ unsigned h2_lds[600];       // [k2][r] packed half2
  __shared__ float g_lds[3][4][1200];    // [split][r][gatecol]

  float crs[3] = {0.f, 0.f, 0.f};        // c-state for up to 3 owned units

  for (int e = tid; e < 600; e += 480) h2_lds[e] = 0u;
  __syncthreads();

  for (int t = 0; t < 64; t++) {
    const int tg = dirb ? (63 - t) : t;

    if (active) {
      // early-issue x-gate loads (s==0 only); consumed at partial write-back
      float4 gxa[4], gxb[4];
      if (s == 0) {
        const float* gxt = gx + ((size_t)tg * NB + n0) * 1200 + 8 * c;
#pragma unroll
        for (int r = 0; r < 4; r++) {
          gxa[r] = *(const float4*)(gxt + (size_t)r * 1200);
          gxb[r] = *(const float4*)(gxt + (size_t)r * 1200 + 4);
        }
      }

      float acc[4][8];
#pragma unroll
      for (int r = 0; r < 4; r++)
#pragma unroll
        for (int j = 0; j < 8; j++) acc[r][j] = 0.f;

      // pipeline buffers: 5 k-pairs per group, 10 groups
      const uint4* wp = WT + (size_t)k2base * 300 + 2 * c;
      float4 wbuf[10], wnxt[10];
      float4 hbuf[5], hnxt[5];
#pragma unroll
      for (int p = 0; p < 5; p++) {
        wbuf[2 * p]     = *(const float4*)(wp + (size_t)p * 300);
        wbuf[2 * p + 1] = *(const float4*)(wp + (size_t)p * 300 + 1);
        hbuf[p] = *(const float4*)&h2_lds[(k2base + p) * 4];
      }
      const uint4* wpn = wp + 5 * 300;

      for (int g = 0; g < 10; g++) {
        if (g < 9) {
#pragma unroll
          for (int p = 0; p < 5; p++) {
            wnxt[2 * p]     = *(const float4*)(wpn + (size_t)p * 300);
            wnxt[2 * p + 1] = *(const float4*)(wpn + (size_t)p * 300 + 1);
            hnxt[p] = *(const float4*)&h2_lds[(k2base + (g + 1) * 5 + p) * 4];
          }
          wpn += 5 * 300;
        }
#pragma unroll
        for (int p = 0; p < 5; p++) {
          F4H2 hh; hh.f = hbuf[p];
          F4H2 w0; w0.f = wbuf[2 * p];
          F4H2 w1; w1.f = wbuf[2 * p + 1];
#pragma unroll
          for (int r = 0; r < 4; r++) {
            acc[r][0] = fdot2f(hh.h[r], w0.h[0], acc[r][0]);
            acc[r][1] = fdot2f(hh.h[r], w0.h[1], acc[r][1]);
            acc[r][2] = fdot2f(hh.h[r], w0.h[2], acc[r][2]);
            acc[r][3] = fdot2f(hh.h[r], w0.h[3], acc[r][3]);
            acc[r][4] = fdot2f(hh.h[r], w1.h[0], acc[r][4]);
            acc[r][5] = fdot2f(hh.h[r], w1.h[1], acc[r][5]);
            acc[r][6] = fdot2f(hh.h[r], w1.h[2], acc[r][6]);
            acc[r][7] = fdot2f(hh.h[r], w1.h[3], acc[r][7]);
          }
        }
#pragma unroll
        for (int p = 0; p < 5; p++) {
          wbuf[2 * p] = wnxt[2 * p];
          wbuf[2 * p + 1] = wnxt[2 * p + 1];
          hbuf[p] = hnxt[p];
        }
      }

      // partial write-back: g_lds[s][r][8c..8c+7]
#pragma unroll
      for (int r = 0; r < 4; r++) {
        float4 v0 = make_float4(acc[r][0], acc[r][1], acc[r][2], acc[r][3]);
        float4 v1 = make_float4(acc[r][4], acc[r][5], acc[r][6], acc[r][7]);
        if (s == 0) {
          v0.x += gxa[r].x; v0.y += gxa[r].y; v0.z += gxa[r].z; v0.w += gxa[r].w;
          v1.x += gxb[r].x; v1.y += gxb[r].y; v1.z += gxb[r].z; v1.w += gxb[r].w;
        }
        *(float4*)&g_lds[s][r][8 * c]     = v0;
        *(float4*)&g_lds[s][r][8 * c + 4] = v1;
      }
    }
    __syncthreads();

    // elementwise: up to 3 units/thread
#pragma unroll
    for (int q = 0; q < 3; q++) {
      int u = tid + q * 480;
      if (u < 1200) {
        int r = u / 300, k = u - r * 300;
        float gi = g_lds[0][r][k]       + g_lds[1][r][k]       + g_lds[2][r][k];
        float gf = g_lds[0][r][300 + k] + g_lds[1][r][300 + k] + g_lds[2][r][300 + k];
        float gg = g_lds[0][r][600 + k] + g_lds[1][r][600 + k] + g_lds[2][r][600 + k];
        float go = g_lds[0][r][900 + k] + g_lds[1][r][900 + k] + g_lds[2][r][900 + k];
        float si = 1.f / (1.f + expf(-gi));
        float sf = 1.f / (1.f + expf(-gf));
        float so = 1.f / (1.f + expf(-go));
        float cc = sf * crs[q] + si * tanhf(gg);
        float h = so * tanhf(cc);
        crs[q] = cc;
        // packed f16 h for next-step recurrence
        ((_Float16*)h2_lds)[(k >> 1) * 8 + r * 2 + (k & 1)] = (_Float16)h;
        if (hist) hist[((size_t)tg * NB + n0 + r) * 300 + k] = h;
        if (hfin && t == 63) hfin[((size_t)dirb * NB + n0 + r) * 300 + k] = h;
      }
    }
    __syncthreads();
  }
}

// ---------------------------------------------------------------------------
__global__ void embed_kernel(
    const int* __restrict__ prem, const int* __restrict__ hyp,
    const float* __restrict__ embW, float* __restrict__ comb)
{
  size_t i = (size_t)blockIdx.x * 256 + threadIdx.x;
  if (i >= (size_t)64 * 256 * 75) return;
  int d4 = (int)(i % 75);
  size_t r = i / 75;
  int n = (int)(r % 256);
  int t = (int)(r / 256);
  int id = (n < 128) ? prem[t * 128 + n] : hyp[t * 128 + (n - 128)];
  float4 v = *(const float4*)(embW + (size_t)id * 300 + d4 * 4);
  *(float4*)(comb + ((size_t)t * 256 + n) * 300 + d4 * 4) = v;
}

// ---------------------------------------------------------------------------
// norm4: weighted norms for all four W sets per (dir,t,n,l) + plain row norms.
// ---------------------------------------------------------------------------
__global__ __launch_bounds__(320) void norm4_kernel(
    const float* __restrict__ hs_fw, const float* __restrict__ hs_bw,
    const float* __restrict__ mp_W,
    float* __restrict__ nm4, float* __restrict__ pnorm)
{
  const int t = blockIdx.x, n = blockIdx.y, dir = blockIdx.z;
  const float* HS = dir ? hs_bw : hs_fw;
  const float* row = HS + ((size_t)t * 256 + n) * 300;
  __shared__ float sh[300];
  const int tid = threadIdx.x, g = tid >> 4, lane = tid & 15;
  for (int k = tid; k < 300; k += 320) sh[k] = row[k];
  __syncthreads();
  if (g == 0) {
    float s2 = 0.f;
    for (int k = lane; k < 300; k += 16) { float x = sh[k]; s2 += x * x; }
    for (int o = 8; o; o >>= 1) s2 += __shfl_down(s2, o, 16);
    if (lane == 0) pnorm[((size_t)dir * 64 + t) * 256 + n] = sqrtf(s2);
  }
#pragma unroll
  for (int wset = 0; wset < 4; wset++) {
    const float* W = mp_W + dir * 24000 + wset * 6000 + g * 300;
    float s1 = 0.f;
    for (int k = lane; k < 300; k += 16) {
      float x = sh[k];
      float w = W[k];
      s1 += x * x * w * w;
    }
    for (int o = 8; o; o >>= 1) s1 += __shfl_down(s1, o, 16);
    if (lane == 0)
      nm4[((((size_t)dir * 4 + wset) * 64 + t) * 256 + n) * 20 + g] = sqrtf(s1);
  }
}

// ---------------------------------------------------------------------------
// att: per (b,z), att[64,64] cosine GEMM -> normalized w (watt) + argmax idx.
// ---------------------------------------------------------------------------
__global__ __launch_bounds__(256) void att_kernel(
    const float* __restrict__ hs_fw, const float* __restrict__ hs_bw,
    const float* __restrict__ pnorm,
    float* __restrict__ watt, int* __restrict__ idxbuf)
{
  const int b = blockIdx.x, z = blockIdx.y;
  const int dir = z & 1;
  const float* HS = dir ? hs_bw : hs_fw;
  const int p_n = (z < 2) ? b : 128 + b;
  const int h_n = (z < 2) ? 128 + b : b;
  const float* pnD = pnorm + (size_t)dir * 16384;

  __shared__ float pch[64 * 100];
  __shared__ float hch[64 * 100];
  __shared__ float att[64 * 65];
  __shared__ float winv_sh[64];

  const int tid = threadIdx.x;
  const int i = tid >> 4, j = tid & 15;
  float acc[4][4];
#pragma unroll
  for (int a = 0; a < 4; a++)
#pragma unroll
    for (int c = 0; c < 4; c++) acc[a][c] = 0.f;

  for (int kc = 0; kc < 300; kc += 100) {
    for (int e = tid; e < 1600; e += 256) {
      int row = e / 25, kq = e - row * 25;
      float4 v = *(const float4*)(HS + ((size_t)row * 256 + p_n) * 300 + kc + kq * 4);
      *(float4*)&pch[row * 100 + kq * 4] = v;
      float4 w = *(const float4*)(HS + ((size_t)row * 256 + h_n) * 300 + kc + kq * 4);
      *(float4*)&hch[row * 100 + kq * 4] = w;
    }
    __syncthreads();
#pragma unroll 5
    for (int kq = 0; kq < 25; kq++) {
      float4 av[4], bv[4];
#pragma unroll
      for (int a = 0; a < 4; a++) av[a] = *(const float4*)&pch[(i + 16 * a) * 100 + kq * 4];
#pragma unroll
      for (int c = 0; c < 4; c++) bv[c] = *(const float4*)&hch[(j + 16 * c) * 100 + kq * 4];
#pragma unroll
      for (int a = 0; a < 4; a++)
#pragma unroll
        for (int c = 0; c < 4; c++)
          acc[a][c] += av[a].x * bv[c].x + av[a].y * bv[c].y + av[a].z * bv[c].z + av[a].w * bv[c].w;
    }
    __syncthreads();
  }

#pragma unroll
  for (int a = 0; a < 4; a++) {
    int t = i + 16 * a;
    float pn = pnD[t * 256 + p_n] + EPSF;
#pragma unroll
    for (int c = 0; c < 4; c++) {
      int s = j + 16 * c;
      float hn = pnD[s * 256 + h_n] + EPSF;
      att[t * 65 + s] = acc[a][c] / (pn * hn);
    }
  }
  __syncthreads();
  if (tid < 64) {
    int t = tid;
    float ssum = 0.f, mx = -1e30f; int mi = 0;
    for (int s = 0; s < 64; s++) {
      float a = att[t * 65 + s];
      ssum += a;
      if (a > mx) { mx = a; mi = s; }
    }
    winv_sh[t] = 1.f / (ssum + EPSF);
    idxbuf[((size_t)z * 128 + b) * 64 + t] = mi;
  }
  __syncthreads();
  for (int e = tid; e < 4096; e += 256) {
    int t = e >> 6, s = e & 63;
    watt[((size_t)z * 128 + b) * 4096 + t * 64 + s] = att[t * 65 + s] * winv_sh[t];
  }
}

// ---------------------------------------------------------------------------
// hmean: per (b,z): hmean[t,k] = sum_s w[t,s]*h[s,k]
// ---------------------------------------------------------------------------
__global__ __launch_bounds__(256) void hmean_kernel(
    const float* __restrict__ hs_fw, const float* __restrict__ hs_bw,
    const float* __restrict__ watt, float* __restrict__ hmeanbuf)
{
  const int b = blockIdx.x, z = blockIdx.y;
  const int dir = z & 1;
  const float* HS = dir ? hs_bw : hs_fw;
  const int h_n = (z < 2) ? 128 + b : b;

  __shared__ float wsh[64 * 65];
  __shared__ float hch[64 * 128];

  const int tid = threadIdx.x;
  const int ti = tid >> 4, kj = tid & 15;
  const float* wsrc = watt + ((size_t)z * 128 + b) * 4096;
  for (int e = tid; e < 4096; e += 256) {
    int t = e >> 6, s = e & 63;
    wsh[t * 65 + s] = wsrc[t * 64 + s];
  }

  for (int kbase = 0; kbase < 300; kbase += 128) {
    int kw = min(128, 300 - kbase);
    int nf4 = kw >> 2;  // 32,32,11
    __syncthreads();
    for (int e = tid; e < 64 * nf4; e += 256) {
      int row = e / nf4, q = e - row * nf4;
      float4 v = *(const float4*)(HS + ((size_t)row * 256 + h_n) * 300 + kbase + q * 4);
      *(float4*)&hch[row * 128 + q * 4] = v;
    }
    __syncthreads();
    float acc[4][8];
#pragma unroll
    for (int a = 0; a < 4; a++)
#pragma unroll
      for (int c = 0; c < 8; c++) acc[a][c] = 0.f;
    for (int s = 0; s < 64; s++) {
      float4 h0 = *(const float4*)&hch[s * 128 + 4 * kj];
      float4 h1 = *(const float4*)&hch[s * 128 + 4 * (kj + 16)];
#pragma unroll
      for (int a = 0; a < 4; a++) {
        float w = wsh[(4 * ti + a) * 65 + s];
        acc[a][0] += w * h0.x; acc[a][1] += w * h0.y; acc[a][2] += w * h0.z; acc[a][3] += w * h0.w;
        acc[a][4] += w * h1.x; acc[a][5] += w * h1.y; acc[a][6] += w * h1.z; acc[a][7] += w * h1.w;
      }
    }
#pragma unroll
    for (int a = 0; a < 4; a++) {
      int t = 4 * ti + a;
#pragma unroll
      for (int c = 0; c < 2; c++) {
        int kq = kj + 16 * c;
        if (kq * 4 < kw) {
          int k = kbase + kq * 4;
          float4 v = make_float4(acc[a][4 * c], acc[a][4 * c + 1], acc[a][4 * c + 2], acc[a][4 * c + 3]);
          *(float4*)&hmeanbuf[(((size_t)z * 128 + b) * 64 + t) * 300 + k] = v;
        }
      }
    }
  }
}

// ---------------------------------------------------------------------------
// maxp: per (b,z,tt): num[t,s,l] GEMM with register tiles, fused max over s.
// ---------------------------------------------------------------------------
__global__ __launch_bounds__(128) void maxp_kernel(
    const float* __restrict__ hs_fw, const float* __restrict__ hs_bw,
    const float* __restrict__ mp_W, const float* __restrict__ nm4,
    float* __restrict__ m_out)
{
  const int b = blockIdx.x, z = blockIdx.y, tt = blockIdx.z;
  const int dir = z & 1;
  const float* HS = dir ? hs_bw : hs_fw;
  const int p_n = (z < 2) ? b : 128 + b;
  const int h_n = (z < 2) ? 128 + b : b;
  const int t_base = tt * 8;
  const float* Wm = mp_W + dir * 24000 + 6000;

  __shared__ float psh[8 * 100];
  __shared__ float hsh[64 * 100];
  __shared__ float wsh[20 * 100];

  const int tid = threadIdx.x;
  const int t_loc = tid >> 4;
  const int sg = (tid >> 1) & 7;
  const int lg = tid & 1;
  const int t = t_base + t_loc;

  float acc[8][10];
#pragma unroll
  for (int i = 0; i < 8; i++)
#pragma unroll
    for (int j = 0; j < 10; j++) acc[i][j] = 0.f;

  for (int kc = 0; kc < 300; kc += 100) {
    for (int e = tid; e < 200; e += 128) {
      int row = e / 25, q = e - row * 25;
      float4 v = *(const float4*)(HS + ((size_t)(t_base + row) * 256 + p_n) * 300 + kc + q * 4);
      *(float4*)&psh[row * 100 + q * 4] = v;
    }
    for (int e = tid; e < 1600; e += 128) {
      int row = e / 25, q = e - row * 25;
      float4 v = *(const float4*)(HS + ((size_t)row * 256 + h_n) * 300 + kc + q * 4);
      *(float4*)&hsh[row * 100 + q * 4] = v;
    }
    for (int e = tid; e < 500; e += 128) {
      int row = e / 25, q = e - row * 25;
      float4 w = *(const float4*)(Wm + (size_t)row * 300 + kc + q * 4);
      w.x *= w.x; w.y *= w.y; w.z *= w.z; w.w *= w.w;
      *(float4*)&wsh[row * 100 + q * 4] = w;
    }
    __syncthreads();
    for (int kq = 0; kq < 25; kq++) {
      float4 pv = *(const float4*)&psh[t_loc * 100 + kq * 4];
      float4 hv[8];
#pragma unroll
      for (int i = 0; i < 8; i++) hv[i] = *(const float4*)&hsh[(sg + 8 * i) * 100 + kq * 4];
#pragma unroll
      for (int j = 0; j < 10; j++) {
        float4 wv = *(const float4*)&wsh[(lg * 10 + j) * 100 + kq * 4];
        float pwx = pv.x * wv.x, pwy = pv.y * wv.y, pwz = pv.z * wv.z, pww = pv.w * wv.w;
#pragma unroll
        for (int i = 0; i < 8; i++)
          acc[i][j] += hv[i].x * pwx + hv[i].y * pwy + hv[i].z * pwz + hv[i].w * pww;
      }
    }
    __syncthreads();
  }

  const float* nmD = nm4 + ((size_t)dir * 4 + 1) * 327680;
  float pn[10], rmax[10];
#pragma unroll
  for (int j = 0; j < 10; j++) {
    pn[j] = nmD[((size_t)t * 256 + p_n) * 20 + lg * 10 + j];
    rmax[j] = -1e30f;
  }
#pragma unroll
  for (int i = 0; i < 8; i++) {
    int s = sg + 8 * i;
#pragma unroll
    for (int j = 0; j < 10; j++) {
      float hn = nmD[((size_t)s * 256 + h_n) * 20 + lg * 10 + j];
      float r = acc[i][j] / (pn[j] * hn + EPSF);
      rmax[j] = fmaxf(rmax[j], r);
    }
  }
#pragma unroll
  for (int off = 8; off >= 2; off >>= 1)
#pragma unroll
    for (int j = 0; j < 10; j++)
      rmax[j] = fmaxf(rmax[j], __shfl_down(rmax[j], off));
  if (sg == 0) {
    float* mrow = m_out + ((size_t)t * 128 + b) * 320 + z * 80;
#pragma unroll
    for (int j = 0; j < 10; j++) mrow[20 + lg * 10 + j] = rmax[j];
  }
}

// ---------------------------------------------------------------------------
// rest: per (b,z): full / attm / maxattm for all t. W^2 staged once in LDS.
// ---------------------------------------------------------------------------
__global__ __launch_bounds__(320) void rest_kernel(
    const float* __restrict__ hs_fw, const float* __restrict__ hs_bw,
    const float* __restrict__ mp_W, const float* __restrict__ nm4,
    const float* __restrict__ hmeanbuf, const int* __restrict__ idxbuf,
    float* __restrict__ m_out)
{
  const int b = blockIdx.x, z = blockIdx.y;
  const int dir = z & 1;
  const float* HS = dir ? hs_bw : hs_fw;
  const int p_n = (z < 2) ? b : 128 + b;
  const int h_n = (z < 2) ? 128 + b : b;
  const int v_t = dir ? 0 : 63;

  __shared__ float w2f[6000], w2a[6000], w2m[6000];
  __shared__ float vsh[300], psh[300], hmsh[300], hxsh[300];

  const int tid = threadIdx.x;
  const int g = tid >> 4, lane = tid & 15;
  const float* Wf = mp_W + dir * 24000;
  const float* Wa = Wf + 12000;
  const float* Wma = Wf + 18000;
  for (int e = tid; e < 6000; e += 320) {
    float a = Wf[e], bb = Wa[e], c = Wma[e];
    w2f[e] = a * a; w2a[e] = bb * bb; w2m[e] = c * c;
  }
  for (int e = tid; e < 300; e += 320)
    vsh[e] = HS[((size_t)v_t * 256 + h_n) * 300 + e];
  __syncthreads();

  const float* base0 = nm4 + ((size_t)dir * 4 + 0) * 327680;
  const float* base2 = nm4 + ((size_t)dir * 4 + 2) * 327680;
  const float* base3 = nm4 + ((size_t)dir * 4 + 3) * 327680;
  const float vnf = base0[((size_t)v_t * 256 + h_n) * 20 + g];

  for (int t = 0; t < 64; t++) {
    int idx = idxbuf[((size_t)z * 128 + b) * 64 + t];
    __syncthreads();
    for (int e = tid; e < 300; e += 320) {
      psh[e] = HS[((size_t)t * 256 + p_n) * 300 + e];
      hmsh[e] = hmeanbuf[(((size_t)z * 128 + b) * 64 + t) * 300 + e];
      hxsh[e] = HS[((size_t)idx * 256 + h_n) * 300 + e];
    }
    __syncthreads();
    float nf = 0.f, na = 0.f, qa = 0.f, nm = 0.f;
#pragma unroll
    for (int c = 0; c < 5; c++) {
      int k4 = lane + 16 * c;
      if (k4 < 75) {
        float4 p = *(const float4*)&psh[4 * k4];
        float4 v = *(const float4*)&vsh[4 * k4];
        float4 hm = *(const float4*)&hmsh[4 * k4];
        float4 hx = *(const float4*)&hxsh[4 * k4];
        float4 wf = *(const float4*)&w2f[g * 300 + 4 * k4];
        float4 wa = *(const float4*)&w2a[g * 300 + 4 * k4];
        float4 wm = *(const float4*)&w2m[g * 300 + 4 * k4];
        nf += p.x * v.x * wf.x + p.y * v.y * wf.y + p.z * v.z * wf.z + p.w * v.w * wf.w;
        na += p.x * hm.x * wa.x + p.y * hm.y * wa.y + p.z * hm.z * wa.z + p.w * hm.w * wa.w;
        qa += hm.x * hm.x * wa.x + hm.y * hm.y * wa.y + hm.z * hm.z * wa.z + hm.w * hm.w * wa.w;
        nm += p.x * hx.x * wm.x + p.y * hx.y * wm.y + p.z * hx.z * wm.z + p.w * hx.w * wm.w;
      }
    }
#pragma unroll
    for (int o = 8; o; o >>= 1) {
      nf += __shfl_down(nf, o);
      na += __shfl_down(na, o);
      qa += __shfl_down(qa, o);
      nm += __shfl_down(nm, o);
    }
    if (lane == 0) {
      float pnf = base0[((size_t)t * 256 + p_n) * 20 + g];
      float pna = base2[((size_t)t * 256 + p_n) * 20 + g];
      float pnm = base3[((size_t)t * 256 + p_n) * 20 + g];
      float qnm = base3[((size_t)idx * 256 + h_n) * 20 + g];
      float* mrow = m_out + ((size_t)t * 128 + b) * 320 + z * 80;
      mrow[g] = nf / (pnf * vnf + EPSF);
      mrow[40 + g] = na / (pna * sqrtf(qa) + EPSF);
      mrow[60 + g] = nm / (pnm * qnm + EPSF);
    }
  }
}

// ---------------------------------------------------------------------------
__global__ __launch_bounds__(256) void mlp_kernel(
    const float* __restrict__ shA0, const float* __restrict__ shA1,
    const float* __restrict__ bnG, const float* __restrict__ bnB,
    const float* __restrict__ W1, const float* __restrict__ b1,
    const float* __restrict__ W2, const float* __restrict__ b2,
    const float* __restrict__ outW, const float* __restrict__ outb,
    float* __restrict__ out)
{
  const int b = blockIdx.x;
  const int tid = threadIdx.x;
  __shared__ float x0[600], x1[600];
  const float inv = 1.0f / sqrtf(1.0f + 1e-5f);
  for (int j = tid; j < 600; j += 256) {
    float v = (j < 300) ? shA0[b * 300 + j] : shA1[b * 300 + (j - 300)];
    x0[j] = bnG[j] * v * inv + bnB[j];
  }
  __syncthreads();
  for (int j = tid; j < 600; j += 256) {
    float acc = b1[j];
    const float* w = W1 + (size_t)j * 600;
    for (int k = 0; k < 600; k++) acc += x0[k] * w[k];
    float r = fmaxf(acc, 0.f);
    x1[j] = bnG[600 + j] * r * inv + bnB[600 + j];
  }
  __syncthreads();
  for (int j = tid; j < 600; j += 256) {
    float acc = b2[j];
    const float* w = W2 + (size_t)j * 600;
    for (int k = 0; k < 600; k++) acc += x1[k] * w[k];
    float r = fmaxf(acc, 0.f);
    x0[j] = bnG[1200 + j] * r * inv + bnB[1200 + j];
  }
  __syncthreads();
  if (tid < 3) {
    float acc = outb[tid];
    const float* w = outW + tid * 600;
    for (int k = 0; k < 600; k++) acc += x0[k] * w[k];
    out[b * 3 + tid] = acc;
  }
}

// ---------------------------------------------------------------------------
extern "C" void kernel_launch(void* const* d_in, const int* in_sizes, int n_in,
                              void* d_out, int out_size, void* d_ws, size_t ws_size,
                              hipStream_t stream) {
  const int* premise = (const int*)d_in[0];
  const int* hypothesis = (const int*)d_in[1];
  const float* embW = (const float*)d_in[2];
  const float* cWih = (const float*)d_in[3];
  const float* cWhh = (const float*)d_in[4];
  const float* cb = (const float*)d_in[5];
  const float* mpW = (const float*)d_in[6];
  const float* aWihF = (const float*)d_in[7];
  const float* aWhhF = (const float*)d_in[8];
  const float* abF = (const float*)d_in[9];
  const float* aWihB = (const float*)d_in[10];
  const float* aWhhB = (const float*)d_in[11];
  const float* abB = (const float*)d_in[12];
  const float* bnG = (const float*)d_in[13];
  const float* bnB = (const float*)d_in[14];
  const float* W1 = (const float*)d_in[15];
  const float* b1 = (const float*)d_in[16];
  const float* W2 = (const float*)d_in[17];
  const float* b2 = (const float*)d_in[18];
  const float* outW = (const float*)d_in[19];
  const float* outb = (const float*)d_in[20];
  float* out = (float*)d_out;

  float* ws = (float*)d_ws;
  // workspace layout (floats)
  float* comb  = ws + 0;           // 4,915,200  (T,256,300); WT2 packs overlay after ctx-gates GEMM
  float* gates = ws + 4915200;     // 19,660,800 (T,256,1200); overlaid after ctx LSTM
  float* hsfw  = ws + 24576000;    // 4,915,200
  float* hsbw  = ws + 29491200;    // 4,915,200
  float* pnorm = ws + 34406400;    // 32,768    [2][64][256]
  float* mbuf  = ws + 35094528;    // 2,621,440 (T,128,320)
  float* sha   = ws + 38023168;    // 76,800    agg final h [2][128][300]

  // packed f16 weights overlay in comb region (comb dead after ctx-gates GEMM)
  unsigned* WT2ctx = (unsigned*)comb;         // 180,000 u32 (150,1200)
  unsigned* WT2af  = WT2ctx + 180000;         // 180,000
  unsigned* WT2ab  = WT2ctx + 360000;         // 180,000

  // overlays inside the dead ctx-gates region (valid between ctx LSTM and agg GEMMs)
  float* watt     = gates;                 // 2,097,152 [4][128][64][64]
  float* hmeanbuf = gates + 2097152;       // 9,830,400 [4][128][64][300]
  int*   idxbuf   = (int*)(gates + 11927552); // 32,768 [4][128][64]
  float* nm4      = gates + 11960320;      // 2,621,440 [2][4][64][256][20]

  // 1) embed
  embed_kernel<<<dim3(4800), dim3(256), 0, stream>>>(premise, hypothesis, embW, comb);

  // 2) ctx input gates (consumes comb)
  gemm_nt128<<<dim3(10, 128), dim3(256), 0, stream>>>(comb, cWih, cb, gates, 16384, 1200, 300);

  // 3) pack recurrent weights (f16 k-pair) into dead comb region
  pack3_kernel<<<dim3(704, 3), dim3(256), 0, stream>>>(
      cWhh, aWhhF, aWhhB, WT2ctx, WT2af, WT2ab);

  // 4) context LSTM: persistent, R=4, 128 blocks, XCD-partitioned dirs
  lstm_persist5<<<dim3(128), dim3(480), 0, stream>>>(
      (const uint4*)WT2ctx, (const uint4*)WT2ctx, gates, gates,
      hsfw, hsbw, nullptr, 256);

  // 5) norms (all 4 W sets) + plain norms
  norm4_kernel<<<dim3(64, 256, 2), dim3(320), 0, stream>>>(hsfw, hsbw, mpW, nm4, pnorm);

  // 6) matching pipeline
  att_kernel<<<dim3(128, 4), dim3(256), 0, stream>>>(hsfw, hsbw, pnorm, watt, idxbuf);
  hmean_kernel<<<dim3(128, 4), dim3(256), 0, stream>>>(hsfw, hsbw, watt, hmeanbuf);
  maxp_kernel<<<dim3(128, 4, 8), dim3(128), 0, stream>>>(hsfw, hsbw, mpW, nm4, mbuf);
  rest_kernel<<<dim3(128, 4), dim3(320), 0, stream>>>(hsfw, hsbw, mpW, nm4, hmeanbuf, idxbuf, mbuf);

  // 7) agg input gates (overwrite gates region; overlays fully consumed)
  float* gaf = gates;
  float* gab = gates + 9830400;
  gemm_nt128<<<dim3(10, 64), dim3(256), 0, stream>>>(mbuf, aWihF, abF, gaf, 8192, 1200, 320);
  gemm_nt128<<<dim3(10, 64), dim3(256), 0, stream>>>(mbuf, aWihB, abB, gab, 8192, 1200, 320);

  // 8) aggregation LSTM: persistent, R=4, 64 blocks, XCD-partitioned dirs
  lstm_persist5<<<dim3(64), dim3(480), 0, stream>>>(
      (const uint4*)WT2af, (const uint4*)WT2ab, gaf, gab,
      nullptr, nullptr, sha, 128);

  // 9) MLP head
  mlp_kernel<<<dim3(128), dim3(256), 0, stream>>>(
      sha, sha + 38400, bnG, bnB, W1, b1, W2, b2, outW, outb, out);
}

// Round 9
// 3037.974 us; speedup vs baseline: 1.1451x; 1.0395x over previous
//
#include <hip/hip_runtime.h>
#include <cstddef>
#include <cstdint>
#include <math.h>

#define EPSF 1e-8f

// Model dims (fixed): T=64, B=128, D=300, H=300, L=20, AH=300, N2=2B=256

typedef _Float16 half2v __attribute__((ext_vector_type(2)));
union F4H2 { float4 f; half2v h[4]; };
union U4H2 { uint4 u; half2v h[4]; };
union UH2 { unsigned u; half2v h; };

#if defined(__has_builtin)
#if __has_builtin(__builtin_amdgcn_fdot2)
#define HAVE_FDOT2 1
#endif
#endif

__device__ __forceinline__ float fdot2f(half2v a, half2v b, float c) {
#ifdef HAVE_FDOT2
  return __builtin_amdgcn_fdot2(a, b, c, false);
#else
  return c + (float)a.x * (float)b.x + (float)a.y * (float)b.y;
#endif
}

__device__ __forceinline__ unsigned packh2(float a, float b) {
  UH2 v;
  v.h.x = (_Float16)a;
  v.h.y = (_Float16)b;
  return v.u;
}

// ---------------------------------------------------------------------------
// 128x128 NT GEMM (fp32), 8x8 micro, KT=16: C[m,n] = bias[n] + sum A[m,k]B[n,k]
// Input-gate GEMMs stay fp32: f16 here compounds with the f16 recurrence and
// blows the 3e-3 absmax budget (round-8 failure: 1.4e-2).
// ---------------------------------------------------------------------------
__global__ __launch_bounds__(256) void gemm_nt128(
    const float* __restrict__ A, const float* __restrict__ B,
    const float* __restrict__ bias, float* __restrict__ C,
    int M, int N, int K)
{
  __shared__ float As[16][128];
  __shared__ float Bs[16][128];
  const int tid = threadIdx.x;
  const int tx = tid & 15, ty = tid >> 4;
  const int mbase = blockIdx.y << 7, nbase = blockIdx.x << 7;
  const int lm = tid >> 1;          // 0..127
  const int lk = (tid & 1) << 3;    // 0 or 8
  float acc[8][8];
#pragma unroll
  for (int i = 0; i < 8; i++)
#pragma unroll
    for (int j = 0; j < 8; j++) acc[i][j] = 0.f;

  for (int kk = 0; kk < K; kk += 16) {
    {
      int m = mbase + lm;
      const float* src = A + (size_t)m * K;
#pragma unroll
      for (int q = 0; q < 2; q++) {
        int kb = kk + lk + q * 4;
        float4 v = make_float4(0.f, 0.f, 0.f, 0.f);
        if (m < M) {
          if (kb + 4 <= K) {
            v = *(const float4*)(src + kb);
          } else {
            v.x = (kb + 0 < K) ? src[kb + 0] : 0.f;
            v.y = (kb + 1 < K) ? src[kb + 1] : 0.f;
            v.z = (kb + 2 < K) ? src[kb + 2] : 0.f;
            v.w = (kb + 3 < K) ? src[kb + 3] : 0.f;
          }
        }
        As[lk + q * 4 + 0][lm] = v.x;
        As[lk + q * 4 + 1][lm] = v.y;
        As[lk + q * 4 + 2][lm] = v.z;
        As[lk + q * 4 + 3][lm] = v.w;
      }
    }
    {
      int n = nbase + lm;
      const float* src = B + (size_t)n * K;
#pragma unroll
      for (int q = 0; q < 2; q++) {
        int kb = kk + lk + q * 4;
        float4 v = make_float4(0.f, 0.f, 0.f, 0.f);
        if (n < N) {
          if (kb + 4 <= K) {
            v = *(const float4*)(src + kb);
          } else {
            v.x = (kb + 0 < K) ? src[kb + 0] : 0.f;
            v.y = (kb + 1 < K) ? src[kb + 1] : 0.f;
            v.z = (kb + 2 < K) ? src[kb + 2] : 0.f;
            v.w = (kb + 3 < K) ? src[kb + 3] : 0.f;
          }
        }
        Bs[lk + q * 4 + 0][lm] = v.x;
        Bs[lk + q * 4 + 1][lm] = v.y;
        Bs[lk + q * 4 + 2][lm] = v.z;
        Bs[lk + q * 4 + 3][lm] = v.w;
      }
    }
    __syncthreads();
#pragma unroll
    for (int k = 0; k < 16; k++) {
      float4 a0 = *(const float4*)&As[k][ty * 8];
      float4 a1 = *(const float4*)&As[k][ty * 8 + 4];
      float4 b0 = *(const float4*)&Bs[k][tx * 8];
      float4 b1 = *(const float4*)&Bs[k][tx * 8 + 4];
      float av[8] = {a0.x, a0.y, a0.z, a0.w, a1.x, a1.y, a1.z, a1.w};
      float bv[8] = {b0.x, b0.y, b0.z, b0.w, b1.x, b1.y, b1.z, b1.w};
#pragma unroll
      for (int i = 0; i < 8; i++)
#pragma unroll
        for (int j = 0; j < 8; j++) acc[i][j] += av[i] * bv[j];
    }
    __syncthreads();
  }

#pragma unroll
  for (int i = 0; i < 8; i++) {
    int m = mbase + ty * 8 + i;
    if (m >= M) continue;
#pragma unroll
    for (int jq = 0; jq < 2; jq++) {
      int n = nbase + tx * 8 + jq * 4;
      if (n >= N) continue;
      float4 v = make_float4(acc[i][jq * 4], acc[i][jq * 4 + 1],
                             acc[i][jq * 4 + 2], acc[i][jq * 4 + 3]);
      if (bias) {
        v.x += bias[n]; v.y += bias[n + 1]; v.z += bias[n + 2]; v.w += bias[n + 3];
      }
      *(float4*)(C + (size_t)m * N + n) = v;
    }
  }
}

// ---------------------------------------------------------------------------
// pack3: W (1200,300) fp32 -> WT2 packed f16 k-pairs: WT2[k2*1200+n].
// ---------------------------------------------------------------------------
__global__ __launch_bounds__(256) void pack3_kernel(
    const float* __restrict__ W0, const float* __restrict__ W1,
    const float* __restrict__ W2,
    unsigned* __restrict__ T0, unsigned* __restrict__ T1,
    unsigned* __restrict__ T2)
{
  int i = blockIdx.x * 256 + threadIdx.x;
  if (i >= 180000) return;
  const float* W = (blockIdx.y == 0) ? W0 : (blockIdx.y == 1) ? W1 : W2;
  unsigned* T = (blockIdx.y == 0) ? T0 : (blockIdx.y == 1) ? T1 : T2;
  int k2 = i / 1200, n = i - k2 * 1200;
  float a = W[(size_t)n * 300 + 2 * k2];
  float b = W[(size_t)n * 300 + 2 * k2 + 1];
  T[i] = packh2(a, b);
}

// ---------------------------------------------------------------------------
// Persistent LSTM v5 (f16 dot2, high occupancy): R=4 rows/block, 64 steps.
// 960 threads = 3 K-splits (50 k-pairs) x 320 (300 active, 4 cols/thread).
// XCD-partitioned: xcd = b&7, dir = xcd>>2, row-group = (b>>3)*4 + (xcd&3).
// Weight ring 5 k-pairs deep; h inline from LDS (packed half2).
// fp32 accumulate / c-state / outputs. LDS = 60.0 KB, 15 waves/CU.
// ---------------------------------------------------------------------------
__global__ __launch_bounds__(960, 1) void lstm_persist6(
    const uint4* __restrict__ WT0, const uint4* __restrict__ WT1,  // packed (150,1200)
    const float* __restrict__ gx0, const float* __restrict__ gx1,  // (64,NB,1200)
    float* __restrict__ hist0, float* __restrict__ hist1,          // (64,NB,300) or null
    float* __restrict__ hfin,                                      // (2,NB,300) or null
    int NB)
{
  const int b = blockIdx.x;
  const int xcd = b & 7;
  const int grp = b >> 3;
  const int dirb = xcd >> 2;
  const int n0 = (grp * 4 + (xcd & 3)) * 4;
  const int tid = threadIdx.x;
  const int s = tid / 320;        // 0..2 K-split
  const int c = tid - s * 320;    // 0..319, active if < 300
  const bool active = (c < 300);
  const int k2base = s * 50;      // k-pair base

  const uint4* WT = dirb ? WT1 : WT0;
  const float* gx = dirb ? gx1 : gx0;
  float* hist = dirb ? hist1 : hist0;

  __shared__ unsigned h2_lds[600];       // [k2][r] packed half2
  __shared__ float g_lds[3][4][1200];    // [split][r][gatecol]

  float crs[2] = {0.f, 0.f};             // c-state for up to 2 owned units

  for (int e = tid; e < 600; e += 960) h2_lds[e] = 0u;
  __syncthreads();

  for (int t = 0; t < 64; t++) {
    const int tg = dirb ? (63 - t) : t;

    if (active) {
      // early-issue x-gate loads (s==0 only); consumed at partial write-back
      float4 gxv[4];
      if (s == 0) {
        const float* gxt = gx + ((size_t)tg * NB + n0) * 1200 + 4 * c;
#pragma unroll
        for (int r = 0; r < 4; r++)
          gxv[r] = *(const float4*)(gxt + (size_t)r * 1200);
      }

      float acc[4][4];
#pragma unroll
      for (int r = 0; r < 4; r++)
#pragma unroll
        for (int j = 0; j < 4; j++) acc[r][j] = 0.f;

      // weight ring: 5 k-pairs/group, 10 groups; h read inline from LDS
      const uint4* wp = WT + (size_t)k2base * 300 + c;
      uint4 wb[5], wn[5];
#pragma unroll
      for (int p = 0; p < 5; p++) wb[p] = wp[(size_t)p * 300];
      const uint4* wpn = wp + 5 * 300;

      for (int g = 0; g < 10; g++) {
        if (g < 9) {
#pragma unroll
          for (int p = 0; p < 5; p++) wn[p] = wpn[(size_t)p * 300];
          wpn += 5 * 300;
        }
#pragma unroll
        for (int p = 0; p < 5; p++) {
          F4H2 hh;
          hh.f = *(const float4*)&h2_lds[(k2base + g * 5 + p) * 4];
          U4H2 w;
          w.u = wb[p];
#pragma unroll
          for (int r = 0; r < 4; r++) {
            acc[r][0] = fdot2f(hh.h[r], w.h[0], acc[r][0]);
            acc[r][1] = fdot2f(hh.h[r], w.h[1], acc[r][1]);
            acc[r][2] = fdot2f(hh.h[r], w.h[2], acc[r][2]);
            acc[r][3] = fdot2f(hh.h[r], w.h[3], acc[r][3]);
          }
        }
#pragma unroll
        for (int p = 0; p < 5; p++) wb[p] = wn[p];
      }

      // partial write-back: g_lds[s][r][4c..4c+3]
#pragma unroll
      for (int r = 0; r < 4; r++) {
        float4 v = make_float4(acc[r][0], acc[r][1], acc[r][2], acc[r][3]);
        if (s == 0) {
          v.x += gxv[r].x; v.y += gxv[r].y; v.z += gxv[r].z; v.w += gxv[r].w;
        }
        *(float4*)&g_lds[s][r][4 * c] = v;
      }
    }
    __syncthreads();

    // elementwise: up to 2 units/thread
#pragma unroll
    for (int q = 0; q < 2; q++) {
      int u = tid + q * 960;
      if (u < 1200) {
        int r = u / 300, k = u - r * 300;
        float gi = g_lds[0][r][k]       + g_lds[1][r][k]       + g_lds[2][r][k];
        float gf = g_lds[0][r][300 + k] + g_lds[1][r][300 + k] + g_lds[2][r][300 + k];
        float gg = g_lds[0][r][600 + k] + g_lds[1][r][600 + k] + g_lds[2][r][600 + k];
        float go = g_lds[0][r][900 + k] + g_lds[1][r][900 + k] + g_lds[2][r][900 + k];
        float si = 1.f / (1.f + expf(-gi));
        float sf = 1.f / (1.f + expf(-gf));
        float so = 1.f / (1.f + expf(-go));
        float cc = sf * crs[q] + si * tanhf(gg);
        float h = so * tanhf(cc);
        crs[q] = cc;
        ((_Float16*)h2_lds)[(k >> 1) * 8 + r * 2 + (k & 1)] = (_Float16)h;
        if (hist) hist[((size_t)tg * NB + n0 + r) * 300 + k] = h;
        if (hfin && t == 63) hfin[((size_t)dirb * NB + n0 + r) * 300 + k] = h;
      }
    }
    __syncthreads();
  }
}

// ---------------------------------------------------------------------------
__global__ void embed_kernel(
    const int* __restrict__ prem, const int* __restrict__ hyp,
    const float* __restrict__ embW, float* __restrict__ comb)
{
  size_t i = (size_t)blockIdx.x * 256 + threadIdx.x;
  if (i >= (size_t)64 * 256 * 75) return;
  int d4 = (int)(i % 75);
  size_t r = i / 75;
  int n = (int)(r % 256);
  int t = (int)(r / 256);
  int id = (n < 128) ? prem[t * 128 + n] : hyp[t * 128 + (n - 128)];
  float4 v = *(const float4*)(embW + (size_t)id * 300 + d4 * 4);
  *(float4*)(comb + ((size_t)t * 256 + n) * 300 + d4 * 4) = v;
}

// ---------------------------------------------------------------------------
// norm4: weighted norms for all four W sets per (dir,t,n,l) + plain row norms.
// ---------------------------------------------------------------------------
__global__ __launch_bounds__(320) void norm4_kernel(
    const float* __restrict__ hs_fw, const float* __restrict__ hs_bw,
    const float* __restrict__ mp_W,
    float* __restrict__ nm4, float* __restrict__ pnorm)
{
  const int t = blockIdx.x, n = blockIdx.y, dir = blockIdx.z;
  const float* HS = dir ? hs_bw : hs_fw;
  const float* row = HS + ((size_t)t * 256 + n) * 300;
  __shared__ float sh[300];
  const int tid = threadIdx.x, g = tid >> 4, lane = tid & 15;
  for (int k = tid; k < 300; k += 320) sh[k] = row[k];
  __syncthreads();
  if (g == 0) {
    float s2 = 0.f;
    for (int k = lane; k < 300; k += 16) { float x = sh[k]; s2 += x * x; }
    for (int o = 8; o; o >>= 1) s2 += __shfl_down(s2, o, 16);
    if (lane == 0) pnorm[((size_t)dir * 64 + t) * 256 + n] = sqrtf(s2);
  }
#pragma unroll
  for (int wset = 0; wset < 4; wset++) {
    const float* W = mp_W + dir * 24000 + wset * 6000 + g * 300;
    float s1 = 0.f;
    for (int k = lane; k < 300; k += 16) {
      float x = sh[k];
      float w = W[k];
      s1 += x * x * w * w;
    }
    for (int o = 8; o; o >>= 1) s1 += __shfl_down(s1, o, 16);
    if (lane == 0)
      nm4[((((size_t)dir * 4 + wset) * 64 + t) * 256 + n) * 20 + g] = sqrtf(s1);
  }
}

// ---------------------------------------------------------------------------
// att: per (b,z), att[64,64] cosine GEMM -> normalized w (watt) + argmax idx.
// ---------------------------------------------------------------------------
__global__ __launch_bounds__(256) void att_kernel(
    const float* __restrict__ hs_fw, const float* __restrict__ hs_bw,
    const float* __restrict__ pnorm,
    float* __restrict__ watt, int* __restrict__ idxbuf)
{
  const int b = blockIdx.x, z = blockIdx.y;
  const int dir = z & 1;
  const float* HS = dir ? hs_bw : hs_fw;
  const int p_n = (z < 2) ? b : 128 + b;
  const int h_n = (z < 2) ? 128 + b : b;
  const float* pnD = pnorm + (size_t)dir * 16384;

  __shared__ float pch[64 * 100];
  __shared__ float hch[64 * 100];
  __shared__ float att[64 * 65];
  __shared__ float winv_sh[64];

  const int tid = threadIdx.x;
  const int i = tid >> 4, j = tid & 15;
  float acc[4][4];
#pragma unroll
  for (int a = 0; a < 4; a++)
#pragma unroll
    for (int c = 0; c < 4; c++) acc[a][c] = 0.f;

  for (int kc = 0; kc < 300; kc += 100) {
    for (int e = tid; e < 1600; e += 256) {
      int row = e / 25, kq = e - row * 25;
      float4 v = *(const float4*)(HS + ((size_t)row * 256 + p_n) * 300 + kc + kq * 4);
      *(float4*)&pch[row * 100 + kq * 4] = v;
      float4 w = *(const float4*)(HS + ((size_t)row * 256 + h_n) * 300 + kc + kq * 4);
      *(float4*)&hch[row * 100 + kq * 4] = w;
    }
    __syncthreads();
#pragma unroll 5
    for (int kq = 0; kq < 25; kq++) {
      float4 av[4], bv[4];
#pragma unroll
      for (int a = 0; a < 4; a++) av[a] = *(const float4*)&pch[(i + 16 * a) * 100 + kq * 4];
#pragma unroll
      for (int c = 0; c < 4; c++) bv[c] = *(const float4*)&hch[(j + 16 * c) * 100 + kq * 4];
#pragma unroll
      for (int a = 0; a < 4; a++)
#pragma unroll
        for (int c = 0; c < 4; c++)
          acc[a][c] += av[a].x * bv[c].x + av[a].y * bv[c].y + av[a].z * bv[c].z + av[a].w * bv[c].w;
    }
    __syncthreads();
  }

#pragma unroll
  for (int a = 0; a < 4; a++) {
    int t = i + 16 * a;
    float pn = pnD[t * 256 + p_n] + EPSF;
#pragma unroll
    for (int c = 0; c < 4; c++) {
      int s = j + 16 * c;
      float hn = pnD[s * 256 + h_n] + EPSF;
      att[t * 65 + s] = acc[a][c] / (pn * hn);
    }
  }
  __syncthreads();
  if (tid < 64) {
    int t = tid;
    float ssum = 0.f, mx = -1e30f; int mi = 0;
    for (int s = 0; s < 64; s++) {
      float a = att[t * 65 + s];
      ssum += a;
      if (a > mx) { mx = a; mi = s; }
    }
    winv_sh[t] = 1.f / (ssum + EPSF);
    idxbuf[((size_t)z * 128 + b) * 64 + t] = mi;
  }
  __syncthreads();
  for (int e = tid; e < 4096; e += 256) {
    int t = e >> 6, s = e & 63;
    watt[((size_t)z * 128 + b) * 4096 + t * 64 + s] = att[t * 65 + s] * winv_sh[t];
  }
}

// ---------------------------------------------------------------------------
// hmean: per (b,z): hmean[t,k] = sum_s w[t,s]*h[s,k]
// ---------------------------------------------------------------------------
__global__ __launch_bounds__(256) void hmean_kernel(
    const float* __restrict__ hs_fw, const float* __restrict__ hs_bw,
    const float* __restrict__ watt, float* __restrict__ hmeanbuf)
{
  const int b = blockIdx.x, z = blockIdx.y;
  const int dir = z & 1;
  const float* HS = dir ? hs_bw : hs_fw;
  const int h_n = (z < 2) ? 128 + b : b;

  __shared__ float wsh[64 * 65];
  __shared__ float hch[64 * 128];

  const int tid = threadIdx.x;
  const int ti = tid >> 4, kj = tid & 15;
  const float* wsrc = watt + ((size_t)z * 128 + b) * 4096;
  for (int e = tid; e < 4096; e += 256) {
    int t = e >> 6, s = e & 63;
    wsh[t * 65 + s] = wsrc[t * 64 + s];
  }

  for (int kbase = 0; kbase < 300; kbase += 128) {
    int kw = min(128, 300 - kbase);
    int nf4 = kw >> 2;  // 32,32,11
    __syncthreads();
    for (int e = tid; e < 64 * nf4; e += 256) {
      int row = e / nf4, q = e - row * nf4;
      float4 v = *(const float4*)(HS + ((size_t)row * 256 + h_n) * 300 + kbase + q * 4);
      *(float4*)&hch[row * 128 + q * 4] = v;
    }
    __syncthreads();
    float acc[4][8];
#pragma unroll
    for (int a = 0; a < 4; a++)
#pragma unroll
      for (int c = 0; c < 8; c++) acc[a][c] = 0.f;
    for (int s = 0; s < 64; s++) {
      float4 h0 = *(const float4*)&hch[s * 128 + 4 * kj];
      float4 h1 = *(const float4*)&hch[s * 128 + 4 * (kj + 16)];
#pragma unroll
      for (int a = 0; a < 4; a++) {
        float w = wsh[(4 * ti + a) * 65 + s];
        acc[a][0] += w * h0.x; acc[a][1] += w * h0.y; acc[a][2] += w * h0.z; acc[a][3] += w * h0.w;
        acc[a][4] += w * h1.x; acc[a][5] += w * h1.y; acc[a][6] += w * h1.z; acc[a][7] += w * h1.w;
      }
    }
#pragma unroll
    for (int a = 0; a < 4; a++) {
      int t = 4 * ti + a;
#pragma unroll
      for (int c = 0; c < 2; c++) {
        int kq = kj + 16 * c;
        if (kq * 4 < kw) {
          int k = kbase + kq * 4;
          float4 v = make_float4(acc[a][4 * c], acc[a][4 * c + 1], acc[a][4 * c + 2], acc[a][4 * c + 3]);
          *(float4*)&hmeanbuf[(((size_t)z * 128 + b) * 64 + t) * 300 + k] = v;
        }
      }
    }
  }
}

// ---------------------------------------------------------------------------
// maxp: per (b,z,tt): num[t,s,l] GEMM with register tiles, fused max over s.
// ---------------------------------------------------------------------------
__global__ __launch_bounds__(128) void maxp_kernel(
    const float* __restrict__ hs_fw, const float* __restrict__ hs_bw,
    const float* __restrict__ mp_W, const float* __restrict__ nm4,
    float* __restrict__ m_out)
{
  const int b = blockIdx.x, z = blockIdx.y, tt = blockIdx.z;
  const int dir = z & 1;
  const float* HS = dir ? hs_bw : hs_fw;
  const int p_n = (z < 2) ? b : 128 + b;
  const int h_n = (z < 2) ? 128 + b : b;
  const int t_base = tt * 8;
  const float* Wm = mp_W + dir * 24000 + 6000;

  __shared__ float psh[8 * 100];
  __shared__ float hsh[64 * 100];
  __shared__ float wsh[20 * 100];

  const int tid = threadIdx.x;
  const int t_loc = tid >> 4;
  const int sg = (tid >> 1) & 7;
  const int lg = tid & 1;
  const int t = t_base + t_loc;

  float acc[8][10];
#pragma unroll
  for (int i = 0; i < 8; i++)
#pragma unroll
    for (int j = 0; j < 10; j++) acc[i][j] = 0.f;

  for (int kc = 0; kc < 300; kc += 100) {
    for (int e = tid; e < 200; e += 128) {
      int row = e / 25, q = e - row * 25;
      float4 v = *(const float4*)(HS + ((size_t)(t_base + row) * 256 + p_n) * 300 + kc + q * 4);
      *(float4*)&psh[row * 100 + q * 4] = v;
    }
    for (int e = tid; e < 1600; e += 128) {
      int row = e / 25, q = e - row * 25;
      float4 v = *(const float4*)(HS + ((size_t)row * 256 + h_n) * 300 + kc + q * 4);
      *(float4*)&hsh[row * 100 + q * 4] = v;
    }
    for (int e = tid; e < 500; e += 128) {
      int row = e / 25, q = e - row * 25;
      float4 w = *(const float4*)(Wm + (size_t)row * 300 + kc + q * 4);
      w.x *= w.x; w.y *= w.y; w.z *= w.z; w.w *= w.w;
      *(float4*)&wsh[row * 100 + q * 4] = w;
    }
    __syncthreads();
    for (int kq = 0; kq < 25; kq++) {
      float4 pv = *(const float4*)&psh[t_loc * 100 + kq * 4];
      float4 hv[8];
#pragma unroll
      for (int i = 0; i < 8; i++) hv[i] = *(const float4*)&hsh[(sg + 8 * i) * 100 + kq * 4];
#pragma unroll
      for (int j = 0; j < 10; j++) {
        float4 wv = *(const float4*)&wsh[(lg * 10 + j) * 100 + kq * 4];
        float pwx = pv.x * wv.x, pwy = pv.y * wv.y, pwz = pv.z * wv.z, pww = pv.w * wv.w;
#pragma unroll
        for (int i = 0; i < 8; i++)
          acc[i][j] += hv[i].x * pwx + hv[i].y * pwy + hv[i].z * pwz + hv[i].w * pww;
      }
    }
    __syncthreads();
  }

  const float* nmD = nm4 + ((size_t)dir * 4 + 1) * 327680;
  float pn[10], rmax[10];
#pragma unroll
  for (int j = 0; j < 10; j++) {
    pn[j] = nmD[((size_t)t * 256 + p_n) * 20 + lg * 10 + j];
    rmax[j] = -1e30f;
  }
#pragma unroll
  for (int i = 0; i < 8; i++) {
    int s = sg + 8 * i;
#pragma unroll
    for (int j = 0; j < 10; j++) {
      float hn = nmD[((size_t)s * 256 + h_n) * 20 + lg * 10 + j];
      float r = acc[i][j] / (pn[j] * hn + EPSF);
      rmax[j] = fmaxf(rmax[j], r);
    }
  }
#pragma unroll
  for (int off = 8; off >= 2; off >>= 1)
#pragma unroll
    for (int j = 0; j < 10; j++)
      rmax[j] = fmaxf(rmax[j], __shfl_down(rmax[j], off));
  if (sg == 0) {
    float* mrow = m_out + ((size_t)t * 128 + b) * 320 + z * 80;
#pragma unroll
    for (int j = 0; j < 10; j++) mrow[20 + lg * 10 + j] = rmax[j];
  }
}

// ---------------------------------------------------------------------------
// rest: per (b,z): full / attm / maxattm for all t. W^2 staged once in LDS.
// ---------------------------------------------------------------------------
__global__ __launch_bounds__(320) void rest_kernel(
    const float* __restrict__ hs_fw, const float* __restrict__ hs_bw,
    const float* __restrict__ mp_W, const float* __restrict__ nm4,
    const float* __restrict__ hmeanbuf, const int* __restrict__ idxbuf,
    float* __restrict__ m_out)
{
  const int b = blockIdx.x, z = blockIdx.y;
  const int dir = z & 1;
  const float* HS = dir ? hs_bw : hs_fw;
  const int p_n = (z < 2) ? b : 128 + b;
  const int h_n = (z < 2) ? 128 + b : b;
  const int v_t = dir ? 0 : 63;

  __shared__ float w2f[6000], w2a[6000], w2m[6000];
  __shared__ float vsh[300], psh[300], hmsh[300], hxsh[300];

  const int tid = threadIdx.x;
  const int g = tid >> 4, lane = tid & 15;
  const float* Wf = mp_W + dir * 24000;
  const float* Wa = Wf + 12000;
  const float* Wma = Wf + 18000;
  for (int e = tid; e < 6000; e += 320) {
    float a = Wf[e], bb = Wa[e], c = Wma[e];
    w2f[e] = a * a; w2a[e] = bb * bb; w2m[e] = c * c;
  }
  for (int e = tid; e < 300; e += 320)
    vsh[e] = HS[((size_t)v_t * 256 + h_n) * 300 + e];
  __syncthreads();

  const float* base0 = nm4 + ((size_t)dir * 4 + 0) * 327680;
  const float* base2 = nm4 + ((size_t)dir * 4 + 2) * 327680;
  const float* base3 = nm4 + ((size_t)dir * 4 + 3) * 327680;
  const float vnf = base0[((size_t)v_t * 256 + h_n) * 20 + g];

  for (int t = 0; t < 64; t++) {
    int idx = idxbuf[((size_t)z * 128 + b) * 64 + t];
    __syncthreads();
    for (int e = tid; e < 300; e += 320) {
      psh[e] = HS[((size_t)t * 256 + p_n) * 300 + e];
      hmsh[e] = hmeanbuf[(((size_t)z * 128 + b) * 64 + t) * 300 + e];
      hxsh[e] = HS[((size_t)idx * 256 + h_n) * 300 + e];
    }
    __syncthreads();
    float nf = 0.f, na = 0.f, qa = 0.f, nm = 0.f;
#pragma unroll
    for (int c = 0; c < 5; c++) {
      int k4 = lane + 16 * c;
      if (k4 < 75) {
        float4 p = *(const float4*)&psh[4 * k4];
        float4 v = *(const float4*)&vsh[4 * k4];
        float4 hm = *(const float4*)&hmsh[4 * k4];
        float4 hx = *(const float4*)&hxsh[4 * k4];
        float4 wf = *(const float4*)&w2f[g * 300 + 4 * k4];
        float4 wa = *(const float4*)&w2a[g * 300 + 4 * k4];
        float4 wm = *(const float4*)&w2m[g * 300 + 4 * k4];
        nf += p.x * v.x * wf.x + p.y * v.y * wf.y + p.z * v.z * wf.z + p.w * v.w * wf.w;
        na += p.x * hm.x * wa.x + p.y * hm.y * wa.y + p.z * hm.z * wa.z + p.w * hm.w * wa.w;
        qa += hm.x * hm.x * wa.x + hm.y * hm.y * wa.y + hm.z * hm.z * wa.z + hm.w * hm.w * wa.w;
        nm += p.x * hx.x * wm.x + p.y * hx.y * wm.y + p.z * hx.z * wm.z + p.w * hx.w * wm.w;
      }
    }
#pragma unroll
    for (int o = 8; o; o >>= 1) {
      nf += __shfl_down(nf, o);
      na += __shfl_down(na, o);
      qa += __shfl_down(qa, o);
      nm += __shfl_down(nm, o);
    }
    if (lane == 0) {
      float pnf = base0[((size_t)t * 256 + p_n) * 20 + g];
      float pna = base2[((size_t)t * 256 + p_n) * 20 + g];
      float pnm = base3[((size_t)t * 256 + p_n) * 20 + g];
      float qnm = base3[((size_t)idx * 256 + h_n) * 20 + g];
      float* mrow = m_out + ((size_t)t * 128 + b) * 320 + z * 80;
      mrow[g] = nf / (pnf * vnf + EPSF);
      mrow[40 + g] = na / (pna * sqrtf(qa) + EPSF);
      mrow[60 + g] = nm / (pnm * qnm + EPSF);
    }
  }
}

// ---------------------------------------------------------------------------
__global__ __launch_bounds__(256) void mlp_kernel(
    const float* __restrict__ shA0, const float* __restrict__ shA1,
    const float* __restrict__ bnG, const float* __restrict__ bnB,
    const float* __restrict__ W1, const float* __restrict__ b1,
    const float* __restrict__ W2, const float* __restrict__ b2,
    const float* __restrict__ outW, const float* __restrict__ outb,
    float* __restrict__ out)
{
  const int b = blockIdx.x;
  const int tid = threadIdx.x;
  __shared__ float x0[600], x1[600];
  const float inv = 1.0f / sqrtf(1.0f + 1e-5f);
  for (int j = tid; j < 600; j += 256) {
    float v = (j < 300) ? shA0[b * 300 + j] : shA1[b * 300 + (j - 300)];
    x0[j] = bnG[j] * v * inv + bnB[j];
  }
  __syncthreads();
  for (int j = tid; j < 600; j += 256) {
    float acc = b1[j];
    const float* w = W1 + (size_t)j * 600;
    for (int k = 0; k < 600; k++) acc += x0[k] * w[k];
    float r = fmaxf(acc, 0.f);
    x1[j] = bnG[600 + j] * r * inv + bnB[600 + j];
  }
  __syncthreads();
  for (int j = tid; j < 600; j += 256) {
    float acc = b2[j];
    const float* w = W2 + (size_t)j * 600;
    for (int k = 0; k < 600; k++) acc += x1[k] * w[k];
    float r = fmaxf(acc, 0.f);
    x0[j] = bnG[1200 + j] * r * inv + bnB[1200 + j];
  }
  __syncthreads();
  if (tid < 3) {
    float acc = outb[tid];
    const float* w = outW + tid * 600;
    for (int k = 0; k < 600; k++) acc += x0[k] * w[k];
    out[b * 3 + tid] = acc;
  }
}

// ---------------------------------------------------------------------------
extern "C" void kernel_launch(void* const* d_in, const int* in_sizes, int n_in,
                              void* d_out, int out_size, void* d_ws, size_t ws_size,
                              hipStream_t stream) {
  const int* premise = (const int*)d_in[0];
  const int* hypothesis = (const int*)d_in[1];
  const float* embW = (const float*)d_in[2];
  const float* cWih = (const float*)d_in[3];
  const float* cWhh = (const float*)d_in[4];
  const float* cb = (const float*)d_in[5];
  const float* mpW = (const float*)d_in[6];
  const float* aWihF = (const float*)d_in[7];
  const float* aWhhF = (const float*)d_in[8];
  const float* abF = (const float*)d_in[9];
  const float* aWihB = (const float*)d_in[10];
  const float* aWhhB = (const float*)d_in[11];
  const float* abB = (const float*)d_in[12];
  const float* bnG = (const float*)d_in[13];
  const float* bnB = (const float*)d_in[14];
  const float* W1 = (const float*)d_in[15];
  const float* b1 = (const float*)d_in[16];
  const float* W2 = (const float*)d_in[17];
  const float* b2 = (const float*)d_in[18];
  const float* outW = (const float*)d_in[19];
  const float* outb = (const float*)d_in[20];
  float* out = (float*)d_out;

  float* ws = (float*)d_ws;
  // workspace layout (floats)
  float* comb  = ws + 0;           // 4,915,200  (T,256,300); WT2 packs overlay after ctx-gates GEMM
  float* gates = ws + 4915200;     // 19,660,800 (T,256,1200); overlaid after ctx LSTM
  float* hsfw  = ws + 24576000;    // 4,915,200
  float* hsbw  = ws + 29491200;    // 4,915,200
  float* pnorm = ws + 34406400;    // 32,768    [2][64][256]
  float* mbuf  = ws + 35094528;    // 2,621,440 (T,128,320)
  float* sha   = ws + 38023168;    // 76,800    agg final h [2][128][300]

  // packed f16 weights overlay in comb region (comb dead after ctx-gates GEMM)
  unsigned* WT2ctx = (unsigned*)comb;         // 180,000 u32 (150,1200)
  unsigned* WT2af  = WT2ctx + 180000;         // 180,000
  unsigned* WT2ab  = WT2ctx + 360000;         // 180,000

  // overlays inside the dead ctx-gates region (valid between ctx LSTM and agg GEMMs)
  float* watt     = gates;                 // 2,097,152 [4][128][64][64]
  float* hmeanbuf = gates + 2097152;       // 9,830,400 [4][128][64][300]
  int*   idxbuf   = (int*)(gates + 11927552); // 32,768 [4][128][64]
  float* nm4      = gates + 11960320;      // 2,621,440 [2][4][64][256][20]

  // 1) embed
  embed_kernel<<<dim3(4800), dim3(256), 0, stream>>>(premise, hypothesis, embW, comb);

  // 2) ctx input gates (consumes comb) — fp32 for accuracy
  gemm_nt128<<<dim3(10, 128), dim3(256), 0, stream>>>(comb, cWih, cb, gates, 16384, 1200, 300);

  // 3) pack recurrent weights (f16 k-pair) into dead comb region
  pack3_kernel<<<dim3(704, 3), dim3(256), 0, stream>>>(
      cWhh, aWhhF, aWhhB, WT2ctx, WT2af, WT2ab);

  // 4) context LSTM: persistent, R=4, 128 blocks, XCD-partitioned dirs
  lstm_persist6<<<dim3(128), dim3(960), 0, stream>>>(
      (const uint4*)WT2ctx, (const uint4*)WT2ctx, gates, gates,
      hsfw, hsbw, nullptr, 256);

  // 5) norms (all 4 W sets) + plain norms
  norm4_kernel<<<dim3(64, 256, 2), dim3(320), 0, stream>>>(hsfw, hsbw, mpW, nm4, pnorm);

  // 6) matching pipeline
  att_kernel<<<dim3(128, 4), dim3(256), 0, stream>>>(hsfw, hsbw, pnorm, watt, idxbuf);
  hmean_kernel<<<dim3(128, 4), dim3(256), 0, stream>>>(hsfw, hsbw, watt, hmeanbuf);
  maxp_kernel<<<dim3(128, 4, 8), dim3(128), 0, stream>>>(hsfw, hsbw, mpW, nm4, mbuf);
  rest_kernel<<<dim3(128, 4), dim3(320), 0, stream>>>(hsfw, hsbw, mpW, nm4, hmeanbuf, idxbuf, mbuf);

  // 7) agg input gates — fp32 for accuracy
  float* gaf = gates;
  float* gab = gates + 9830400;
  gemm_nt128<<<dim3(10, 64), dim3(256), 0, stream>>>(mbuf, aWihF, abF, gaf, 8192, 1200, 320);
  gemm_nt128<<<dim3(10, 64), dim3(256), 0, stream>>>(mbuf, aWihB, abB, gab, 8192, 1200, 320);

  // 8) aggregation LSTM: persistent, R=4, 64 blocks, XCD-partitioned dirs
  lstm_persist6<<<dim3(64), dim3(960), 0, stream>>>(
      (const uint4*)WT2af, (const uint4*)WT2ab, gaf, gab,
      nullptr, nullptr, sha, 128);

  // 9) MLP head
  mlp_kernel<<<dim3(128), dim3(256), 0, stream>>>(
      sha, sha + 38400, bnG, bnB, W1, b1, W2, b2, outW, outb, out);
}

// Round 10
// 2717.440 us; speedup vs baseline: 1.2802x; 1.1180x over previous
//
#include <hip/hip_runtime.h>
#include <cstddef>
#include <cstdint>
#include <math.h>

#define EPSF 1e-8f

// Model dims (fixed): T=64, B=128, D=300, H=300, L=20, AH=300, N2=2B=256

typedef _Float16 half8v __attribute__((ext_vector_type(8)));
typedef float f32x4v __attribute__((ext_vector_type(4)));
union U4H8 { uint4 u; half8v h; _Float16 e[8]; };

// ---------------------------------------------------------------------------
// 128x128 NT GEMM (fp32), 8x8 micro, KT=16: C[m,n] = bias[n] + sum A[m,k]B[n,k]
// Input-gate GEMMs stay fp32: f16 here compounds with the f16 recurrence and
// blows the 3e-3 absmax budget (round-8 failure: 1.4e-2).
// ---------------------------------------------------------------------------
__global__ __launch_bounds__(256) void gemm_nt128(
    const float* __restrict__ A, const float* __restrict__ B,
    const float* __restrict__ bias, float* __restrict__ C,
    int M, int N, int K)
{
  __shared__ float As[16][128];
  __shared__ float Bs[16][128];
  const int tid = threadIdx.x;
  const int tx = tid & 15, ty = tid >> 4;
  const int mbase = blockIdx.y << 7, nbase = blockIdx.x << 7;
  const int lm = tid >> 1;          // 0..127
  const int lk = (tid & 1) << 3;    // 0 or 8
  float acc[8][8];
#pragma unroll
  for (int i = 0; i < 8; i++)
#pragma unroll
    for (int j = 0; j < 8; j++) acc[i][j] = 0.f;

  for (int kk = 0; kk < K; kk += 16) {
    {
      int m = mbase + lm;
      const float* src = A + (size_t)m * K;
#pragma unroll
      for (int q = 0; q < 2; q++) {
        int kb = kk + lk + q * 4;
        float4 v = make_float4(0.f, 0.f, 0.f, 0.f);
        if (m < M) {
          if (kb + 4 <= K) {
            v = *(const float4*)(src + kb);
          } else {
            v.x = (kb + 0 < K) ? src[kb + 0] : 0.f;
            v.y = (kb + 1 < K) ? src[kb + 1] : 0.f;
            v.z = (kb + 2 < K) ? src[kb + 2] : 0.f;
            v.w = (kb + 3 < K) ? src[kb + 3] : 0.f;
          }
        }
        As[lk + q * 4 + 0][lm] = v.x;
        As[lk + q * 4 + 1][lm] = v.y;
        As[lk + q * 4 + 2][lm] = v.z;
        As[lk + q * 4 + 3][lm] = v.w;
      }
    }
    {
      int n = nbase + lm;
      const float* src = B + (size_t)n * K;
#pragma unroll
      for (int q = 0; q < 2; q++) {
        int kb = kk + lk + q * 4;
        float4 v = make_float4(0.f, 0.f, 0.f, 0.f);
        if (n < N) {
          if (kb + 4 <= K) {
            v = *(const float4*)(src + kb);
          } else {
            v.x = (kb + 0 < K) ? src[kb + 0] : 0.f;
            v.y = (kb + 1 < K) ? src[kb + 1] : 0.f;
            v.z = (kb + 2 < K) ? src[kb + 2] : 0.f;
            v.w = (kb + 3 < K) ? src[kb + 3] : 0.f;
          }
        }
        Bs[lk + q * 4 + 0][lm] = v.x;
        Bs[lk + q * 4 + 1][lm] = v.y;
        Bs[lk + q * 4 + 2][lm] = v.z;
        Bs[lk + q * 4 + 3][lm] = v.w;
      }
    }
    __syncthreads();
#pragma unroll
    for (int k = 0; k < 16; k++) {
      float4 a0 = *(const float4*)&As[k][ty * 8];
      float4 a1 = *(const float4*)&As[k][ty * 8 + 4];
      float4 b0 = *(const float4*)&Bs[k][tx * 8];
      float4 b1 = *(const float4*)&Bs[k][tx * 8 + 4];
      float av[8] = {a0.x, a0.y, a0.z, a0.w, a1.x, a1.y, a1.z, a1.w};
      float bv[8] = {b0.x, b0.y, b0.z, b0.w, b1.x, b1.y, b1.z, b1.w};
#pragma unroll
      for (int i = 0; i < 8; i++)
#pragma unroll
        for (int j = 0; j < 8; j++) acc[i][j] += av[i] * bv[j];
    }
    __syncthreads();
  }

#pragma unroll
  for (int i = 0; i < 8; i++) {
    int m = mbase + ty * 8 + i;
    if (m >= M) continue;
#pragma unroll
    for (int jq = 0; jq < 2; jq++) {
      int n = nbase + tx * 8 + jq * 4;
      if (n >= N) continue;
      float4 v = make_float4(acc[i][jq * 4], acc[i][jq * 4 + 1],
                             acc[i][jq * 4 + 2], acc[i][jq * 4 + 3]);
      if (bias) {
        v.x += bias[n]; v.y += bias[n + 1]; v.z += bias[n + 2]; v.w += bias[n + 3];
      }
      *(float4*)(C + (size_t)m * N + n) = v;
    }
  }
}

// ---------------------------------------------------------------------------
// packB: W (1200,300) fp32 -> MFMA B-fragment stream for 16x16x32_f16.
// Gate-interleaved column order col' = 4*u + gate  (orig n = gate*300+u).
// Item i = (nt*10+kt)*64 + lane; lane holds B[k = kt*32+(lane>>4)*8+j][col'=
// nt*16+(lane&15)] for j=0..7, f16, zero-padded for k>=300.
// ---------------------------------------------------------------------------
__global__ __launch_bounds__(256) void packB_kernel(
    const float* __restrict__ W0, const float* __restrict__ W1,
    const float* __restrict__ W2,
    uint4* __restrict__ T0, uint4* __restrict__ T1, uint4* __restrict__ T2)
{
  int i = blockIdx.x * 256 + threadIdx.x;
  if (i >= 48000) return;
  const float* W = (blockIdx.y == 0) ? W0 : (blockIdx.y == 1) ? W1 : W2;
  uint4* T = (blockIdx.y == 0) ? T0 : (blockIdx.y == 1) ? T1 : T2;
  int lane = i & 63;
  int tile = i >> 6;               // nt*10 + kt
  int nt = tile / 10, kt = tile - nt * 10;
  int lm = lane & 15, lg = lane >> 4;
  int colp = nt * 16 + lm;
  int u = colp >> 2, gate = colp & 3;
  int n = gate * 300 + u;
  U4H8 v;
#pragma unroll
  for (int j = 0; j < 8; j++) {
    int k = kt * 32 + lg * 8 + j;
    float x = (k < 300) ? W[(size_t)n * 300 + k] : 0.f;
    v.e[j] = (_Float16)x;
  }
  T[i] = v.u;
}

// ---------------------------------------------------------------------------
// Persistent LSTM via MFMA (16x16x32 f16): R=8 rows/block, all 64 steps.
// 512 threads = 8 waves; wave w owns N-tiles nt = w, w+8, ... (<75).
// XCD-partitioned: xcd = b&7, dir = xcd>>2, rowgroup = (b>>3)*4 + (xcd&3).
// h in LDS as A-fragment layout [16][328] f16 (rows 8-15 & k>=300 zero).
// Gates staged [1200 cols'][9 pad] f32; gate cols interleaved col'=4u+gate.
// gx prefetched to regs at step top (orig [i|f|g|o] layout). fp32 c-state.
// LDS = 43.2 KB + 10.5 KB = 53.7 KB.
// ---------------------------------------------------------------------------
__global__ __launch_bounds__(512, 1) void lstm_mfma(
    const uint4* __restrict__ WB0, const uint4* __restrict__ WB1, // packed B-frags
    const float* __restrict__ gx0, const float* __restrict__ gx1, // (64,NB,1200)
    float* __restrict__ hist0, float* __restrict__ hist1,         // (64,NB,300) or null
    float* __restrict__ hfin,                                     // (2,NB,300) or null
    int NB)
{
  const int b = blockIdx.x;
  const int xcd = b & 7;
  const int grp = b >> 3;
  const int dirb = xcd >> 2;
  const int n0 = (grp * 4 + (xcd & 3)) * 8;
  const int tid = threadIdx.x;
  const int wv = tid >> 6, lane = tid & 63;
  const int lm = lane & 15, lg = lane >> 4;

  const uint4* WB = dirb ? WB1 : WB0;
  const float* gx = dirb ? gx1 : gx0;
  float* hist = dirb ? hist1 : hist0;

  __shared__ _Float16 hA[16 * 328];   // [m][k], pitch 328
  __shared__ float gsh[1200 * 9];     // [col'][m(pad 9)]

  for (int e = tid; e < 16 * 328; e += 512) hA[e] = (_Float16)0.f;
  __syncthreads();

  const int nnt = (wv < 3) ? 10 : 9;  // 75 N-tiles over 8 waves

  float crs[5] = {0.f, 0.f, 0.f, 0.f, 0.f};

  for (int t = 0; t < 64; t++) {
    const int tg = dirb ? (63 - t) : t;

    // prefetch x-gates for this thread's elementwise units (consumed post-barrier)
    float gxi[5], gxf[5], gxg[5], gxo[5];
#pragma unroll
    for (int q = 0; q < 5; q++) {
      int e = tid + q * 512;
      if (e < 2400) {
        int m = e / 300, u = e - m * 300;
        const float* gxt = gx + ((size_t)tg * NB + n0 + m) * 1200;
        gxi[q] = gxt[u];
        gxf[q] = gxt[300 + u];
        gxg[q] = gxt[600 + u];
        gxo[q] = gxt[900 + u];
      } else {
        gxi[q] = gxf[q] = gxg[q] = gxo[q] = 0.f;
      }
    }

    // A-fragment cache: a[kt] = hA[m=lm][kt*32 + lg*8 .. +7]
    U4H8 afrag[10];
#pragma unroll
    for (int kt = 0; kt < 10; kt++)
      afrag[kt].u = *(const uint4*)&hA[lm * 328 + kt * 32 + lg * 8];

    // MFMA over this wave's N-tiles, one-tile-ahead B prefetch
    uint4 bcur[10], bnxt[10];
#pragma unroll
    for (int kt = 0; kt < 10; kt++)
      bcur[kt] = WB[(size_t)(wv * 10 + kt) * 64 + lane];

    for (int i = 0; i < nnt; i++) {
      int nt = wv + 8 * i;
      if (i + 1 < nnt) {
        int ntn = nt + 8;
#pragma unroll
        for (int kt = 0; kt < 10; kt++)
          bnxt[kt] = WB[(size_t)((ntn * 10 + kt) * 64 + lane)];
      }
      f32x4v acc = {0.f, 0.f, 0.f, 0.f};
#pragma unroll
      for (int kt = 0; kt < 10; kt++) {
        U4H8 bb; bb.u = bcur[kt];
        acc = __builtin_amdgcn_mfma_f32_16x16x32_f16(afrag[kt].h, bb.h, acc, 0, 0, 0);
      }
      // D: col'=nt*16+lm, m=lg*4+r; keep m<8 (rows 8-15 are zero-padding)
      if (lg < 2) {
#pragma unroll
        for (int r = 0; r < 4; r++)
          gsh[(nt * 16 + lm) * 9 + lg * 4 + r] = acc[r];
      }
#pragma unroll
      for (int kt = 0; kt < 10; kt++) bcur[kt] = bnxt[kt];
    }
    __syncthreads();

    // elementwise: e = m*300 + u; up to 5 units/thread
#pragma unroll
    for (int q = 0; q < 5; q++) {
      int e = tid + q * 512;
      if (e < 2400) {
        int m = e / 300, u = e - m * 300;
        float gi = gxi[q] + gsh[(4 * u + 0) * 9 + m];
        float gf = gxf[q] + gsh[(4 * u + 1) * 9 + m];
        float gg = gxg[q] + gsh[(4 * u + 2) * 9 + m];
        float go = gxo[q] + gsh[(4 * u + 3) * 9 + m];
        float si = 1.f / (1.f + expf(-gi));
        float sf = 1.f / (1.f + expf(-gf));
        float so = 1.f / (1.f + expf(-go));
        float cc = sf * crs[q] + si * tanhf(gg);
        float h = so * tanhf(cc);
        crs[q] = cc;
        hA[m * 328 + u] = (_Float16)h;
        if (hist) hist[((size_t)tg * NB + n0 + m) * 300 + u] = h;
        if (hfin && t == 63) hfin[((size_t)dirb * NB + n0 + m) * 300 + u] = h;
      }
    }
    __syncthreads();
  }
}

// ---------------------------------------------------------------------------
__global__ void embed_kernel(
    const int* __restrict__ prem, const int* __restrict__ hyp,
    const float* __restrict__ embW, float* __restrict__ comb)
{
  size_t i = (size_t)blockIdx.x * 256 + threadIdx.x;
  if (i >= (size_t)64 * 256 * 75) return;
  int d4 = (int)(i % 75);
  size_t r = i / 75;
  int n = (int)(r % 256);
  int t = (int)(r / 256);
  int id = (n < 128) ? prem[t * 128 + n] : hyp[t * 128 + (n - 128)];
  float4 v = *(const float4*)(embW + (size_t)id * 300 + d4 * 4);
  *(float4*)(comb + ((size_t)t * 256 + n) * 300 + d4 * 4) = v;
}

// ---------------------------------------------------------------------------
// norm4: weighted norms for all four W sets per (dir,t,n,l) + plain row norms.
// ---------------------------------------------------------------------------
__global__ __launch_bounds__(320) void norm4_kernel(
    const float* __restrict__ hs_fw, const float* __restrict__ hs_bw,
    const float* __restrict__ mp_W,
    float* __restrict__ nm4, float* __restrict__ pnorm)
{
  const int t = blockIdx.x, n = blockIdx.y, dir = blockIdx.z;
  const float* HS = dir ? hs_bw : hs_fw;
  const float* row = HS + ((size_t)t * 256 + n) * 300;
  __shared__ float sh[300];
  const int tid = threadIdx.x, g = tid >> 4, lane = tid & 15;
  for (int k = tid; k < 300; k += 320) sh[k] = row[k];
  __syncthreads();
  if (g == 0) {
    float s2 = 0.f;
    for (int k = lane; k < 300; k += 16) { float x = sh[k]; s2 += x * x; }
    for (int o = 8; o; o >>= 1) s2 += __shfl_down(s2, o, 16);
    if (lane == 0) pnorm[((size_t)dir * 64 + t) * 256 + n] = sqrtf(s2);
  }
#pragma unroll
  for (int wset = 0; wset < 4; wset++) {
    const float* W = mp_W + dir * 24000 + wset * 6000 + g * 300;
    float s1 = 0.f;
    for (int k = lane; k < 300; k += 16) {
      float x = sh[k];
      float w = W[k];
      s1 += x * x * w * w;
    }
    for (int o = 8; o; o >>= 1) s1 += __shfl_down(s1, o, 16);
    if (lane == 0)
      nm4[((((size_t)dir * 4 + wset) * 64 + t) * 256 + n) * 20 + g] = sqrtf(s1);
  }
}

// ---------------------------------------------------------------------------
// att: per (b,z), att[64,64] cosine GEMM -> normalized w (watt) + argmax idx.
// ---------------------------------------------------------------------------
__global__ __launch_bounds__(256) void att_kernel(
    const float* __restrict__ hs_fw, const float* __restrict__ hs_bw,
    const float* __restrict__ pnorm,
    float* __restrict__ watt, int* __restrict__ idxbuf)
{
  const int b = blockIdx.x, z = blockIdx.y;
  const int dir = z & 1;
  const float* HS = dir ? hs_bw : hs_fw;
  const int p_n = (z < 2) ? b : 128 + b;
  const int h_n = (z < 2) ? 128 + b : b;
  const float* pnD = pnorm + (size_t)dir * 16384;

  __shared__ float pch[64 * 100];
  __shared__ float hch[64 * 100];
  __shared__ float att[64 * 65];
  __shared__ float winv_sh[64];

  const int tid = threadIdx.x;
  const int i = tid >> 4, j = tid & 15;
  float acc[4][4];
#pragma unroll
  for (int a = 0; a < 4; a++)
#pragma unroll
    for (int c = 0; c < 4; c++) acc[a][c] = 0.f;

  for (int kc = 0; kc < 300; kc += 100) {
    for (int e = tid; e < 1600; e += 256) {
      int row = e / 25, kq = e - row * 25;
      float4 v = *(const float4*)(HS + ((size_t)row * 256 + p_n) * 300 + kc + kq * 4);
      *(float4*)&pch[row * 100 + kq * 4] = v;
      float4 w = *(const float4*)(HS + ((size_t)row * 256 + h_n) * 300 + kc + kq * 4);
      *(float4*)&hch[row * 100 + kq * 4] = w;
    }
    __syncthreads();
#pragma unroll 5
    for (int kq = 0; kq < 25; kq++) {
      float4 av[4], bv[4];
#pragma unroll
      for (int a = 0; a < 4; a++) av[a] = *(const float4*)&pch[(i + 16 * a) * 100 + kq * 4];
#pragma unroll
      for (int c = 0; c < 4; c++) bv[c] = *(const float4*)&hch[(j + 16 * c) * 100 + kq * 4];
#pragma unroll
      for (int a = 0; a < 4; a++)
#pragma unroll
        for (int c = 0; c < 4; c++)
          acc[a][c] += av[a].x * bv[c].x + av[a].y * bv[c].y + av[a].z * bv[c].z + av[a].w * bv[c].w;
    }
    __syncthreads();
  }

#pragma unroll
  for (int a = 0; a < 4; a++) {
    int t = i + 16 * a;
    float pn = pnD[t * 256 + p_n] + EPSF;
#pragma unroll
    for (int c = 0; c < 4; c++) {
      int s = j + 16 * c;
      float hn = pnD[s * 256 + h_n] + EPSF;
      att[t * 65 + s] = acc[a][c] / (pn * hn);
    }
  }
  __syncthreads();
  if (tid < 64) {
    int t = tid;
    float ssum = 0.f, mx = -1e30f; int mi = 0;
    for (int s = 0; s < 64; s++) {
      float a = att[t * 65 + s];
      ssum += a;
      if (a > mx) { mx = a; mi = s; }
    }
    winv_sh[t] = 1.f / (ssum + EPSF);
    idxbuf[((size_t)z * 128 + b) * 64 + t] = mi;
  }
  __syncthreads();
  for (int e = tid; e < 4096; e += 256) {
    int t = e >> 6, s = e & 63;
    watt[((size_t)z * 128 + b) * 4096 + t * 64 + s] = att[t * 65 + s] * winv_sh[t];
  }
}

// ---------------------------------------------------------------------------
// hmean: per (b,z): hmean[t,k] = sum_s w[t,s]*h[s,k]
// ---------------------------------------------------------------------------
__global__ __launch_bounds__(256) void hmean_kernel(
    const float* __restrict__ hs_fw, const float* __restrict__ hs_bw,
    const float* __restrict__ watt, float* __restrict__ hmeanbuf)
{
  const int b = blockIdx.x, z = blockIdx.y;
  const int dir = z & 1;
  const float* HS = dir ? hs_bw : hs_fw;
  const int h_n = (z < 2) ? 128 + b : b;

  __shared__ float wsh[64 * 65];
  __shared__ float hch[64 * 128];

  const int tid = threadIdx.x;
  const int ti = tid >> 4, kj = tid & 15;
  const float* wsrc = watt + ((size_t)z * 128 + b) * 4096;
  for (int e = tid; e < 4096; e += 256) {
    int t = e >> 6, s = e & 63;
    wsh[t * 65 + s] = wsrc[t * 64 + s];
  }

  for (int kbase = 0; kbase < 300; kbase += 128) {
    int kw = min(128, 300 - kbase);
    int nf4 = kw >> 2;  // 32,32,11
    __syncthreads();
    for (int e = tid; e < 64 * nf4; e += 256) {
      int row = e / nf4, q = e - row * nf4;
      float4 v = *(const float4*)(HS + ((size_t)row * 256 + h_n) * 300 + kbase + q * 4);
      *(float4*)&hch[row * 128 + q * 4] = v;
    }
    __syncthreads();
    float acc[4][8];
#pragma unroll
    for (int a = 0; a < 4; a++)
#pragma unroll
      for (int c = 0; c < 8; c++) acc[a][c] = 0.f;
    for (int s = 0; s < 64; s++) {
      float4 h0 = *(const float4*)&hch[s * 128 + 4 * kj];
      float4 h1 = *(const float4*)&hch[s * 128 + 4 * (kj + 16)];
#pragma unroll
      for (int a = 0; a < 4; a++) {
        float w = wsh[(4 * ti + a) * 65 + s];
        acc[a][0] += w * h0.x; acc[a][1] += w * h0.y; acc[a][2] += w * h0.z; acc[a][3] += w * h0.w;
        acc[a][4] += w * h1.x; acc[a][5] += w * h1.y; acc[a][6] += w * h1.z; acc[a][7] += w * h1.w;
      }
    }
#pragma unroll
    for (int a = 0; a < 4; a++) {
      int t = 4 * ti + a;
#pragma unroll
      for (int c = 0; c < 2; c++) {
        int kq = kj + 16 * c;
        if (kq * 4 < kw) {
          int k = kbase + kq * 4;
          float4 v = make_float4(acc[a][4 * c], acc[a][4 * c + 1], acc[a][4 * c + 2], acc[a][4 * c + 3]);
          *(float4*)&hmeanbuf[(((size_t)z * 128 + b) * 64 + t) * 300 + k] = v;
        }
      }
    }
  }
}

// ---------------------------------------------------------------------------
// maxp: per (b,z,tt): num[t,s,l] GEMM with register tiles, fused max over s.
// ---------------------------------------------------------------------------
__global__ __launch_bounds__(128) void maxp_kernel(
    const float* __restrict__ hs_fw, const float* __restrict__ hs_bw,
    const float* __restrict__ mp_W, const float* __restrict__ nm4,
    float* __restrict__ m_out)
{
  const int b = blockIdx.x, z = blockIdx.y, tt = blockIdx.z;
  const int dir = z & 1;
  const float* HS = dir ? hs_bw : hs_fw;
  const int p_n = (z < 2) ? b : 128 + b;
  const int h_n = (z < 2) ? 128 + b : b;
  const int t_base = tt * 8;
  const float* Wm = mp_W + dir * 24000 + 6000;

  __shared__ float psh[8 * 100];
  __shared__ float hsh[64 * 100];
  __shared__ float wsh[20 * 100];

  const int tid = threadIdx.x;
  const int t_loc = tid >> 4;
  const int sg = (tid >> 1) & 7;
  const int lg = tid & 1;
  const int t = t_base + t_loc;

  float acc[8][10];
#pragma unroll
  for (int i = 0; i < 8; i++)
#pragma unroll
    for (int j = 0; j < 10; j++) acc[i][j] = 0.f;

  for (int kc = 0; kc < 300; kc += 100) {
    for (int e = tid; e < 200; e += 128) {
      int row = e / 25, q = e - row * 25;
      float4 v = *(const float4*)(HS + ((size_t)(t_base + row) * 256 + p_n) * 300 + kc + q * 4);
      *(float4*)&psh[row * 100 + q * 4] = v;
    }
    for (int e = tid; e < 1600; e += 128) {
      int row = e / 25, q = e - row * 25;
      float4 v = *(const float4*)(HS + ((size_t)row * 256 + h_n) * 300 + kc + q * 4);
      *(float4*)&hsh[row * 100 + q * 4] = v;
    }
    for (int e = tid; e < 500; e += 128) {
      int row = e / 25, q = e - row * 25;
      float4 w = *(const float4*)(Wm + (size_t)row * 300 + kc + q * 4);
      w.x *= w.x; w.y *= w.y; w.z *= w.z; w.w *= w.w;
      *(float4*)&wsh[row * 100 + q * 4] = w;
    }
    __syncthreads();
    for (int kq = 0; kq < 25; kq++) {
      float4 pv = *(const float4*)&psh[t_loc * 100 + kq * 4];
      float4 hv[8];
#pragma unroll
      for (int i = 0; i < 8; i++) hv[i] = *(const float4*)&hsh[(sg + 8 * i) * 100 + kq * 4];
#pragma unroll
      for (int j = 0; j < 10; j++) {
        float4 wv = *(const float4*)&wsh[(lg * 10 + j) * 100 + kq * 4];
        float pwx = pv.x * wv.x, pwy = pv.y * wv.y, pwz = pv.z * wv.z, pww = pv.w * wv.w;
#pragma unroll
        for (int i = 0; i < 8; i++)
          acc[i][j] += hv[i].x * pwx + hv[i].y * pwy + hv[i].z * pwz + hv[i].w * pww;
      }
    }
    __syncthreads();
  }

  const float* nmD = nm4 + ((size_t)dir * 4 + 1) * 327680;
  float pn[10], rmax[10];
#pragma unroll
  for (int j = 0; j < 10; j++) {
    pn[j] = nmD[((size_t)t * 256 + p_n) * 20 + lg * 10 + j];
    rmax[j] = -1e30f;
  }
#pragma unroll
  for (int i = 0; i < 8; i++) {
    int s = sg + 8 * i;
#pragma unroll
    for (int j = 0; j < 10; j++) {
      float hn = nmD[((size_t)s * 256 + h_n) * 20 + lg * 10 + j];
      float r = acc[i][j] / (pn[j] * hn + EPSF);
      rmax[j] = fmaxf(rmax[j], r);
    }
  }
#pragma unroll
  for (int off = 8; off >= 2; off >>= 1)
#pragma unroll
    for (int j = 0; j < 10; j++)
      rmax[j] = fmaxf(rmax[j], __shfl_down(rmax[j], off));
  if (sg == 0) {
    float* mrow = m_out + ((size_t)t * 128 + b) * 320 + z * 80;
#pragma unroll
    for (int j = 0; j < 10; j++) mrow[20 + lg * 10 + j] = rmax[j];
  }
}

// ---------------------------------------------------------------------------
// rest: per (b,z): full / attm / maxattm for all t. W^2 staged once in LDS.
// ---------------------------------------------------------------------------
__global__ __launch_bounds__(320) void rest_kernel(
    const float* __restrict__ hs_fw, const float* __restrict__ hs_bw,
    const float* __restrict__ mp_W, const float* __restrict__ nm4,
    const float* __restrict__ hmeanbuf, const int* __restrict__ idxbuf,
    float* __restrict__ m_out)
{
  const int b = blockIdx.x, z = blockIdx.y;
  const int dir = z & 1;
  const float* HS = dir ? hs_bw : hs_fw;
  const int p_n = (z < 2) ? b : 128 + b;
  const int h_n = (z < 2) ? 128 + b : b;
  const int v_t = dir ? 0 : 63;

  __shared__ float w2f[6000], w2a[6000], w2m[6000];
  __shared__ float vsh[300], psh[300], hmsh[300], hxsh[300];

  const int tid = threadIdx.x;
  const int g = tid >> 4, lane = tid & 15;
  const float* Wf = mp_W + dir * 24000;
  const float* Wa = Wf + 12000;
  const float* Wma = Wf + 18000;
  for (int e = tid; e < 6000; e += 320) {
    float a = Wf[e], bb = Wa[e], c = Wma[e];
    w2f[e] = a * a; w2a[e] = bb * bb; w2m[e] = c * c;
  }
  for (int e = tid; e < 300; e += 320)
    vsh[e] = HS[((size_t)v_t * 256 + h_n) * 300 + e];
  __syncthreads();

  const float* base0 = nm4 + ((size_t)dir * 4 + 0) * 327680;
  const float* base2 = nm4 + ((size_t)dir * 4 + 2) * 327680;
  const float* base3 = nm4 + ((size_t)dir * 4 + 3) * 327680;
  const float vnf = base0[((size_t)v_t * 256 + h_n) * 20 + g];

  for (int t = 0; t < 64; t++) {
    int idx = idxbuf[((size_t)z * 128 + b) * 64 + t];
    __syncthreads();
    for (int e = tid; e < 300; e += 320) {
      psh[e] = HS[((size_t)t * 256 + p_n) * 300 + e];
      hmsh[e] = hmeanbuf[(((size_t)z * 128 + b) * 64 + t) * 300 + e];
      hxsh[e] = HS[((size_t)idx * 256 + h_n) * 300 + e];
    }
    __syncthreads();
    float nf = 0.f, na = 0.f, qa = 0.f, nm = 0.f;
#pragma unroll
    for (int c = 0; c < 5; c++) {
      int k4 = lane + 16 * c;
      if (k4 < 75) {
        float4 p = *(const float4*)&psh[4 * k4];
        float4 v = *(const float4*)&vsh[4 * k4];
        float4 hm = *(const float4*)&hmsh[4 * k4];
        float4 hx = *(const float4*)&hxsh[4 * k4];
        float4 wf = *(const float4*)&w2f[g * 300 + 4 * k4];
        float4 wa = *(const float4*)&w2a[g * 300 + 4 * k4];
        float4 wm = *(const float4*)&w2m[g * 300 + 4 * k4];
        nf += p.x * v.x * wf.x + p.y * v.y * wf.y + p.z * v.z * wf.z + p.w * v.w * wf.w;
        na += p.x * hm.x * wa.x + p.y * hm.y * wa.y + p.z * hm.z * wa.z + p.w * hm.w * wa.w;
        qa += hm.x * hm.x * wa.x + hm.y * hm.y * wa.y + hm.z * hm.z * wa.z + hm.w * hm.w * wa.w;
        nm += p.x * hx.x * wm.x + p.y * hx.y * wm.y + p.z * hx.z * wm.z + p.w * hx.w * wm.w;
      }
    }
#pragma unroll
    for (int o = 8; o; o >>= 1) {
      nf += __shfl_down(nf, o);
      na += __shfl_down(na, o);
      qa += __shfl_down(qa, o);
      nm += __shfl_down(nm, o);
    }
    if (lane == 0) {
      float pnf = base0[((size_t)t * 256 + p_n) * 20 + g];
      float pna = base2[((size_t)t * 256 + p_n) * 20 + g];
      float pnm = base3[((size_t)t * 256 + p_n) * 20 + g];
      float qnm = base3[((size_t)idx * 256 + h_n) * 20 + g];
      float* mrow = m_out + ((size_t)t * 128 + b) * 320 + z * 80;
      mrow[g] = nf / (pnf * vnf + EPSF);
      mrow[40 + g] = na / (pna * sqrtf(qa) + EPSF);
      mrow[60 + g] = nm / (pnm * qnm + EPSF);
    }
  }
}

// ---------------------------------------------------------------------------
__global__ __launch_bounds__(256) void mlp_kernel(
    const float* __restrict__ shA0, const float* __restrict__ shA1,
    const float* __restrict__ bnG, const float* __restrict__ bnB,
    const float* __restrict__ W1, const float* __restrict__ b1,
    const float* __restrict__ W2, const float* __restrict__ b2,
    const float* __restrict__ outW, const float* __restrict__ outb,
    float* __restrict__ out)
{
  const int b = blockIdx.x;
  const int tid = threadIdx.x;
  __shared__ float x0[600], x1[600];
  const float inv = 1.0f / sqrtf(1.0f + 1e-5f);
  for (int j = tid; j < 600; j += 256) {
    float v = (j < 300) ? shA0[b * 300 + j] : shA1[b * 300 + (j - 300)];
    x0[j] = bnG[j] * v * inv + bnB[j];
  }
  __syncthreads();
  for (int j = tid; j < 600; j += 256) {
    float acc = b1[j];
    const float* w = W1 + (size_t)j * 600;
    for (int k = 0; k < 600; k++) acc += x0[k] * w[k];
    float r = fmaxf(acc, 0.f);
    x1[j] = bnG[600 + j] * r * inv + bnB[600 + j];
  }
  __syncthreads();
  for (int j = tid; j < 600; j += 256) {
    float acc = b2[j];
    const float* w = W2 + (size_t)j * 600;
    for (int k = 0; k < 600; k++) acc += x1[k] * w[k];
    float r = fmaxf(acc, 0.f);
    x0[j] = bnG[1200 + j] * r * inv + bnB[1200 + j];
  }
  __syncthreads();
  if (tid < 3) {
    float acc = outb[tid];
    const float* w = outW + tid * 600;
    for (int k = 0; k < 600; k++) acc += x0[k] * w[k];
    out[b * 3 + tid] = acc;
  }
}

// ---------------------------------------------------------------------------
extern "C" void kernel_launch(void* const* d_in, const int* in_sizes, int n_in,
                              void* d_out, int out_size, void* d_ws, size_t ws_size,
                              hipStream_t stream) {
  const int* premise = (const int*)d_in[0];
  const int* hypothesis = (const int*)d_in[1];
  const float* embW = (const float*)d_in[2];
  const float* cWih = (const float*)d_in[3];
  const float* cWhh = (const float*)d_in[4];
  const float* cb = (const float*)d_in[5];
  const float* mpW = (const float*)d_in[6];
  const float* aWihF = (const float*)d_in[7];
  const float* aWhhF = (const float*)d_in[8];
  const float* abF = (const float*)d_in[9];
  const float* aWihB = (const float*)d_in[10];
  const float* aWhhB = (const float*)d_in[11];
  const float* abB = (const float*)d_in[12];
  const float* bnG = (const float*)d_in[13];
  const float* bnB = (const float*)d_in[14];
  const float* W1 = (const float*)d_in[15];
  const float* b1 = (const float*)d_in[16];
  const float* W2 = (const float*)d_in[17];
  const float* b2 = (const float*)d_in[18];
  const float* outW = (const float*)d_in[19];
  const float* outb = (const float*)d_in[20];
  float* out = (float*)d_out;

  float* ws = (float*)d_ws;
  // workspace layout (floats)
  float* comb  = ws + 0;           // 4,915,200  (T,256,300); WB packs overlay after ctx-gates GEMM
  float* gates = ws + 4915200;     // 19,660,800 (T,256,1200); overlaid after ctx LSTM
  float* hsfw  = ws + 24576000;    // 4,915,200
  float* hsbw  = ws + 29491200;    // 4,915,200
  float* pnorm = ws + 34406400;    // 32,768    [2][64][256]
  float* mbuf  = ws + 35094528;    // 2,621,440 (T,128,320)
  float* sha   = ws + 38023168;    // 76,800    agg final h [2][128][300]

  // packed MFMA B-fragment weights overlay in comb region (dead after ctx-gates GEMM)
  // each: 48,000 uint4 = 192,000 float-slots
  uint4* WBctx = (uint4*)comb;
  uint4* WBaf  = (uint4*)(comb + 192000);
  uint4* WBab  = (uint4*)(comb + 384000);

  // overlays inside the dead ctx-gates region (valid between ctx LSTM and agg GEMMs)
  float* watt     = gates;                 // 2,097,152 [4][128][64][64]
  float* hmeanbuf = gates + 2097152;       // 9,830,400 [4][128][64][300]
  int*   idxbuf   = (int*)(gates + 11927552); // 32,768 [4][128][64]
  float* nm4      = gates + 11960320;      // 2,621,440 [2][4][64][256][20]

  // 1) embed
  embed_kernel<<<dim3(4800), dim3(256), 0, stream>>>(premise, hypothesis, embW, comb);

  // 2) ctx input gates (consumes comb) — fp32 for accuracy
  gemm_nt128<<<dim3(10, 128), dim3(256), 0, stream>>>(comb, cWih, cb, gates, 16384, 1200, 300);

  // 3) pack recurrent weights into MFMA B-fragment stream (dead comb region)
  packB_kernel<<<dim3(188, 3), dim3(256), 0, stream>>>(
      cWhh, aWhhF, aWhhB, WBctx, WBaf, WBab);

  // 4) context LSTM: MFMA, R=8, 64 blocks (32/dir), XCD-partitioned dirs
  lstm_mfma<<<dim3(64), dim3(512), 0, stream>>>(
      WBctx, WBctx, gates, gates, hsfw, hsbw, nullptr, 256);

  // 5) norms (all 4 W sets) + plain norms
  norm4_kernel<<<dim3(64, 256, 2), dim3(320), 0, stream>>>(hsfw, hsbw, mpW, nm4, pnorm);

  // 6) matching pipeline
  att_kernel<<<dim3(128, 4), dim3(256), 0, stream>>>(hsfw, hsbw, pnorm, watt, idxbuf);
  hmean_kernel<<<dim3(128, 4), dim3(256), 0, stream>>>(hsfw, hsbw, watt, hmeanbuf);
  maxp_kernel<<<dim3(128, 4, 8), dim3(128), 0, stream>>>(hsfw, hsbw, mpW, nm4, mbuf);
  rest_kernel<<<dim3(128, 4), dim3(320), 0, stream>>>(hsfw, hsbw, mpW, nm4, hmeanbuf, idxbuf, mbuf);

  // 7) agg input gates — fp32 for accuracy
  float* gaf = gates;
  float* gab = gates + 9830400;
  gemm_nt128<<<dim3(10, 64), dim3(256), 0, stream>>>(mbuf, aWihF, abF, gaf, 8192, 1200, 320);
  gemm_nt128<<<dim3(10, 64), dim3(256), 0, stream>>>(mbuf, aWihB, abB, gab, 8192, 1200, 320);

  // 8) aggregation LSTM: MFMA, R=8, 32 blocks (16/dir), XCD-partitioned dirs
  lstm_mfma<<<dim3(32), dim3(512), 0, stream>>>(
      WBaf, WBab, gaf, gab, nullptr, nullptr, sha, 128);

  // 9) MLP head
  mlp_kernel<<<dim3(128), dim3(256), 0, stream>>>(
      sha, sha + 38400, bnG, bnB, W1, b1, W2, b2, outW, outb, out);
}